// Round 11
// baseline (986.276 us; speedup 1.0000x reference)
//
#include <hip/hip_runtime.h>
#include <hip/hip_bf16.h>

using bf16x8 = __attribute__((ext_vector_type(8))) short;
using f32x4  = __attribute__((ext_vector_type(4))) float;
using u16x4  = __attribute__((ext_vector_type(4))) unsigned short;

constexpr int Ht = 60, Wt = 108, C = 512;
constexpr int GWt = 14, NWIN = 112, NTOK = Ht * Wt, BT = 16;
constexpr int NBLK = BT * NWIN;                   // 1792 window blocks
constexpr float SCALE = 0.08838834764831845f;     // 1/sqrt(128)
constexpr size_t WOFF = 4 * 262144;               // weights: 4x512x512 bf16 elems
constexpr size_t SLABE = (size_t)NBLK * 64 * 512; // one slab: elems (bf16)

__device__ __forceinline__ unsigned short f2b(float f) {   // f32 -> bf16 RNE
  union { float f; unsigned u; } v; v.f = f;
  unsigned r = v.u + 0x7fffu + ((v.u >> 16) & 1u);
  return (unsigned short)(r >> 16);
}

__global__ void cvt_weights(const float* __restrict__ a, const float* __restrict__ b,
                            const float* __restrict__ c, const float* __restrict__ d,
                            unsigned short* __restrict__ dst) {
  int i = blockIdx.x * blockDim.x + threadIdx.x;   // 262144 threads, 4 f32 each
  int m  = i >> 16;
  int o4 = i & 65535;
  const float* src = (m == 0) ? a : (m == 1) ? b : (m == 2) ? c : d;
  float4 v = *(const float4*)(src + (size_t)o4 * 4);
  u16x4 o;
  o[0] = f2b(v.x); o[1] = f2b(v.y); o[2] = f2b(v.z); o[3] = f2b(v.w);
  *(u16x4*)(dst + (size_t)m * 262144 + (size_t)o4 * 4) = o;
}

// ============ K0: x f32 -> bf16 window-layout slab (padding zeros baked) ====
extern "C" __global__ void xcvt(const float* __restrict__ x,
                                unsigned short* __restrict__ xs) {
  const int tid = threadIdx.x;
  const int blk = blockIdx.x;
  const int b   = blk / NWIN;
  const int w   = blk - b * NWIN;
  const int wy  = w / GWt, wx = w - wy * GWt;
  unsigned short* dst = xs + (size_t)blk * 32768;
  for (int it = 0; it < 32; ++it) {
    int f  = it * 256 + tid;
    int r  = f >> 7;
    int c4 = f & 127;
    int gy = wy * 8 + (r >> 3), gx = wx * 8 + (r & 7);
    float4 v = make_float4(0.f, 0.f, 0.f, 0.f);
    if (gy < Ht && gx < Wt)
      v = *(const float4*)(x + ((size_t)b * NTOK + gy * Wt + gx) * C + c4 * 4);
    u16x4 o;
    o[0] = f2b(v.x); o[1] = f2b(v.y); o[2] = f2b(v.z); o[3] = f2b(v.w);
    *(u16x4*)(dst + r * 512 + c4 * 4) = o;
  }
}

// ============ K1: LDS-free QKV GEMM. A from bf16 window slab (L2-hot). ======
// Q,K row-major slabs; V transposed [d][tok] into vst (= d_out scratch).
extern "C" __global__ __launch_bounds__(256, 4)
void qkv_gemm(const unsigned short* __restrict__ xs,
              const unsigned short* __restrict__ wbf,   // [4][512][512] bf16
              const float* __restrict__ bq, const float* __restrict__ bk,
              const float* __restrict__ bv,
              unsigned short* __restrict__ qs,
              unsigned short* __restrict__ ks,
              unsigned short* __restrict__ vst)
{
  const int tid   = threadIdx.x;
  const int wvid  = tid >> 6;
  const int lane  = tid & 63;
  const int l15   = lane & 15;
  const int kl    = (lane >> 4) << 3;
  const int rbase = (lane >> 4) << 2;
  const int blk   = blockIdx.x;

  const unsigned short* xa = xs + (size_t)blk * 32768;

  for (int m = 0; m < 3; ++m) {
    const unsigned short* wm = wbf + (size_t)m * 262144;
    const float* bias = (m == 0) ? bq : (m == 1) ? bk : bv;
    for (int half = 0; half < 2; ++half) {
      f32x4 acc[4][4];
      #pragma unroll
      for (int mt = 0; mt < 4; ++mt)
        #pragma unroll
        for (int nt = 0; nt < 4; ++nt) acc[mt][nt] = (f32x4){0.f, 0.f, 0.f, 0.f};
      #pragma unroll 2
      for (int kk = 0; kk < 512; kk += 32) {
        int ka = kk + kl;
        bf16x8 afr[4];
        #pragma unroll
        for (int mt = 0; mt < 4; ++mt)
          afr[mt] = *(const bf16x8*)(xa + (mt * 16 + l15) * 512 + ka);
        bf16x8 bfr[4];
        #pragma unroll
        for (int nt = 0; nt < 4; ++nt) {
          int j = wvid * 128 + half * 64 + nt * 16 + l15;
          bfr[nt] = *(const bf16x8*)(wm + (size_t)j * 512 + ka);
        }
        #pragma unroll
        for (int mt = 0; mt < 4; ++mt)
          #pragma unroll
          for (int nt = 0; nt < 4; ++nt)
            acc[mt][nt] = __builtin_amdgcn_mfma_f32_16x16x32_bf16(afr[mt], bfr[nt], acc[mt][nt], 0, 0, 0);
      }
      if (m < 2) {
        unsigned short* dst = ((m == 0) ? qs : ks) + (size_t)blk * 32768;
        #pragma unroll
        for (int nt = 0; nt < 4; ++nt) {
          int j = wvid * 128 + half * 64 + nt * 16 + l15;
          float bi = bias[j];
          #pragma unroll
          for (int mt = 0; mt < 4; ++mt)
            #pragma unroll
            for (int rg = 0; rg < 4; ++rg) {
              int row = mt * 16 + rbase + rg;
              dst[row * 512 + j] = f2b(acc[mt][nt][rg] + bi);
            }
        }
      } else {
        // V transposed: vst[blk][j][tok], lane's 4 rg = 4 consecutive toks
        unsigned short* dst = vst + (size_t)blk * 32768;
        #pragma unroll
        for (int nt = 0; nt < 4; ++nt) {
          int j = wvid * 128 + half * 64 + nt * 16 + l15;
          float bi = bias[j];
          #pragma unroll
          for (int mt = 0; mt < 4; ++mt) {
            u16x4 pk;
            #pragma unroll
            for (int rg = 0; rg < 4; ++rg) pk[rg] = f2b(acc[mt][nt][rg] + bi);
            *(u16x4*)(dst + j * 64 + mt * 16 + rbase) = pk;
          }
        }
      }
    }
  }
}

// ============ K2: per-(window,head) attention. LDS 24KB (K swz + P swz) =====
// V read directly from transposed slab; attn output aliases the Q slab slice.
extern "C" __global__ __launch_bounds__(256, 4)
void attn2(unsigned short* __restrict__ qs,           // in: Q; out: attn (alias)
           const unsigned short* __restrict__ ks,
           const unsigned short* __restrict__ vst)    // [blk][512 d][64 tok]
{
  __shared__ char kbuf[16384];
  __shared__ char pbf[8192];

  const int tid   = threadIdx.x;
  const int wvid  = tid >> 6;
  const int lane  = tid & 63;
  const int l15   = lane & 15;
  const int kl    = (lane >> 4) << 3;
  const int rbase = (lane >> 4) << 2;

  const int w = blockIdx.x;
  const int h = blockIdx.y;
  unsigned short*       Qs = qs  + (size_t)w * 32768 + h * 128;
  const unsigned short* Ks = ks  + (size_t)w * 32768 + h * 128;
  const unsigned short* Vt = vst + (size_t)w * 32768 + (size_t)(h * 128) * 64;

  // stage K [64][128] -> LDS swizzled (coalesced 16B chunks)
  #pragma unroll
  for (int it = 0; it < 4; ++it) {
    int f  = it * 256 + tid;       // u16x8 chunk; 16 per row
    int r  = f >> 4;
    int c8 = f & 15;
    bf16x8 v = *(const bf16x8*)(Ks + r * 512 + c8 * 8);
    int off = (r << 8) + (c8 << 4); off ^= (r & 7) << 4;
    *(bf16x8*)(kbuf + off) = v;
  }
  __syncthreads();

  // QK^T: wave owns 16 q-rows; Q read straight from slab
  f32x4 sacc[4];
  #pragma unroll
  for (int nt = 0; nt < 4; ++nt) sacc[nt] = (f32x4){0.f, 0.f, 0.f, 0.f};
  #pragma unroll
  for (int kk = 0; kk < 128; kk += 32) {
    int ka = kk + kl;
    bf16x8 afr = *(const bf16x8*)(Qs + (wvid * 16 + l15) * 512 + ka);
    #pragma unroll
    for (int nt = 0; nt < 4; ++nt) {
      int jr = nt * 16 + l15;
      int o2 = (jr << 8) + (ka << 1); o2 ^= (jr & 7) << 4;
      bf16x8 bfr = *(const bf16x8*)(kbuf + o2);
      sacc[nt] = __builtin_amdgcn_mfma_f32_16x16x32_bf16(afr, bfr, sacc[nt], 0, 0, 0);
    }
  }
  // softmax (each row lives in one 16-lane group), P -> LDS
  #pragma unroll
  for (int rg = 0; rg < 4; ++rg) {
    float m = -3.0e38f;
    #pragma unroll
    for (int nt = 0; nt < 4; ++nt) m = fmaxf(m, sacc[nt][rg]);
    #pragma unroll
    for (int dd = 1; dd < 16; dd <<= 1) m = fmaxf(m, __shfl_xor(m, dd, 64));
    float s = 0.f, e[4];
    #pragma unroll
    for (int nt = 0; nt < 4; ++nt) { e[nt] = __expf((sacc[nt][rg] - m) * SCALE); s += e[nt]; }
    #pragma unroll
    for (int dd = 1; dd < 16; dd <<= 1) s += __shfl_xor(s, dd, 64);
    float inv = 1.f / s;
    int row = wvid * 16 + rbase + rg;
    #pragma unroll
    for (int nt = 0; nt < 4; ++nt) {
      int col = nt * 16 + l15;
      int off = (row << 7) + (col << 1); off ^= (row & 7) << 4;
      *(unsigned short*)(pbf + off) = f2b(e[nt] * inv);
    }
  }
  __syncthreads();

  // PV: all 64 rows x wave's 32 d-cols, K=64; V frags direct from global
  f32x4 pacc[4][2];
  #pragma unroll
  for (int mt = 0; mt < 4; ++mt)
    #pragma unroll
    for (int nt = 0; nt < 2; ++nt) pacc[mt][nt] = (f32x4){0.f, 0.f, 0.f, 0.f};
  #pragma unroll
  for (int kk = 0; kk < 64; kk += 32) {
    int ka = kk + kl;
    bf16x8 afr[4];
    #pragma unroll
    for (int mt = 0; mt < 4; ++mt) {
      int row = mt * 16 + l15;
      int off = (row << 7) + (ka << 1); off ^= (row & 7) << 4;
      afr[mt] = *(const bf16x8*)(pbf + off);
    }
    bf16x8 bfr[2];
    #pragma unroll
    for (int nt = 0; nt < 2; ++nt) {
      int d = wvid * 32 + nt * 16 + l15;
      bfr[nt] = *(const bf16x8*)(Vt + d * 64 + ka);
    }
    #pragma unroll
    for (int mt = 0; mt < 4; ++mt)
      #pragma unroll
      for (int nt = 0; nt < 2; ++nt)
        pacc[mt][nt] = __builtin_amdgcn_mfma_f32_16x16x32_bf16(afr[mt], bfr[nt], pacc[mt][nt], 0, 0, 0);
  }
  // write attn over the Q slice (this block is its only reader)
  #pragma unroll
  for (int nt = 0; nt < 2; ++nt) {
    int d = wvid * 32 + nt * 16 + l15;
    #pragma unroll
    for (int mt = 0; mt < 4; ++mt)
      #pragma unroll
      for (int rg = 0; rg < 4; ++rg) {
        int row = mt * 16 + rbase + rg;
        Qs[row * 512 + d] = f2b(pacc[mt][nt][rg]);
      }
  }
}

// ============ K3: out = slab @ Wo^T + bo (window-ordered slab) ==============
extern "C" __global__ __launch_bounds__(256, 2)
void proj_o(const unsigned short* __restrict__ slab,
            const unsigned short* __restrict__ wo,
            const float* __restrict__ bo,
            float* __restrict__ out)
{
  __shared__ char smem[65536];                 // [64][512] bf16, swizzled
  const int tid   = threadIdx.x;
  const int wvid  = tid >> 6;
  const int lane  = tid & 63;
  const int l15   = lane & 15;
  const int kl    = (lane >> 4) << 3;
  const int rbase = (lane >> 4) << 2;

  const int blk = blockIdx.x;
  const int b   = blk / NWIN;
  const int w   = blk - b * NWIN;
  const int wy  = w / GWt, wx = w - wy * GWt;

  const unsigned short* src = slab + (size_t)blk * 32768;
  for (int it = 0; it < 16; ++it) {
    int f  = it * 256 + tid;                   // u16x8 group; 64 per row
    int r  = f >> 6;
    int c8 = f & 63;
    bf16x8 v = *(const bf16x8*)(src + r * 512 + c8 * 8);
    int off = (r << 10) + (c8 << 4);
    off ^= (r & 7) << 4;
    *(bf16x8*)(smem + off) = v;
  }
  __syncthreads();

  for (int half = 0; half < 2; ++half) {
    f32x4 acc[4][4];
    #pragma unroll
    for (int mt = 0; mt < 4; ++mt)
      #pragma unroll
      for (int nt = 0; nt < 4; ++nt) acc[mt][nt] = (f32x4){0.f, 0.f, 0.f, 0.f};
    #pragma unroll 2
    for (int kk = 0; kk < 512; kk += 32) {
      int ka = kk + kl;
      bf16x8 afr[4];
      #pragma unroll
      for (int mt = 0; mt < 4; ++mt) {
        int row = mt * 16 + l15;
        int off = (row << 10) + (ka << 1); off ^= (row & 7) << 4;
        afr[mt] = *(const bf16x8*)(smem + off);
      }
      bf16x8 bfr[4];
      #pragma unroll
      for (int nt = 0; nt < 4; ++nt) {
        int j = wvid * 128 + half * 64 + nt * 16 + l15;
        bfr[nt] = *(const bf16x8*)(wo + (size_t)j * 512 + ka);
      }
      #pragma unroll
      for (int mt = 0; mt < 4; ++mt)
        #pragma unroll
        for (int nt = 0; nt < 4; ++nt)
          acc[mt][nt] = __builtin_amdgcn_mfma_f32_16x16x32_bf16(afr[mt], bfr[nt], acc[mt][nt], 0, 0, 0);
    }
    #pragma unroll
    for (int mt = 0; mt < 4; ++mt)
      #pragma unroll
      for (int rg = 0; rg < 4; ++rg) {
        int r = mt * 16 + rbase + rg;
        int gy = wy * 8 + (r >> 3), gx = wx * 8 + (r & 7);
        if (gy < Ht && gx < Wt) {
          float* po = out + ((size_t)b * NTOK + gy * Wt + gx) * C;
          #pragma unroll
          for (int nt = 0; nt < 4; ++nt) {
            int j = wvid * 128 + half * 64 + nt * 16 + l15;
            po[j] = acc[mt][nt][rg] + bo[j];
          }
        }
      }
  }
}

// ============ TIER 2: round-7 fused per-window kernel (proven, 119MB ws) ====
extern "C" __global__ __launch_bounds__(256, 1)
void qkv_attn(const float* __restrict__ x,
              const unsigned short* __restrict__ wbf,
              const float* __restrict__ bq, const float* __restrict__ bk,
              const float* __restrict__ bv,
              unsigned short* __restrict__ slab)
{
  __shared__ char smem[73728];
  char* qb = smem + 32768;
  char* kb = smem + 49152;
  char* pb = smem + 65536;

  const int tid   = threadIdx.x;
  const int wvid  = tid >> 6;
  const int lane  = tid & 63;
  const int l15   = lane & 15;
  const int kl    = (lane >> 4) << 3;
  const int rbase = (lane >> 4) << 2;

  const int blk = blockIdx.x;
  const int b   = blk / NWIN;
  const int w   = blk - b * NWIN;
  const int wy  = w / GWt, wx = w - wy * GWt;

  for (int it = 0; it < 32; ++it) {
    int f  = it * 256 + tid;
    int r  = f >> 7;
    int c4 = f & 127;
    int gy = wy * 8 + (r >> 3), gx = wx * 8 + (r & 7);
    float4 v = make_float4(0.f, 0.f, 0.f, 0.f);
    if (gy < Ht && gx < Wt)
      v = *(const float4*)(x + ((size_t)b * NTOK + gy * Wt + gx) * C + c4 * 4);
    u16x4 o;
    o[0] = f2b(v.x); o[1] = f2b(v.y); o[2] = f2b(v.z); o[3] = f2b(v.w);
    int lc  = c4 & 63;
    int off = (r << 9) + (lc << 3);
    off ^= (r & 7) << 4;
    off += (c4 >> 6) * 32768;
    *(u16x4*)(smem + off) = o;
  }
  __syncthreads();

  bf16x8 xr[4][8];
  #pragma unroll
  for (int mt = 0; mt < 4; ++mt) {
    int row = mt * 16 + l15;
    #pragma unroll
    for (int s = 0; s < 8; ++s) {
      int off = (row << 9) + ((s * 32 + kl) << 1);
      off ^= (row & 7) << 4;
      xr[mt][s] = *(const bf16x8*)(smem + 32768 + off);
    }
  }
  __syncthreads();

  auto gemm_r = [&](const unsigned short* wm, int h, f32x4 (&acc)[4][2]) {
    #pragma unroll
    for (int mt = 0; mt < 4; ++mt)
      #pragma unroll
      for (int nt = 0; nt < 2; ++nt) acc[mt][nt] = (f32x4){0.f, 0.f, 0.f, 0.f};
    #pragma unroll
    for (int s = 0; s < 16; ++s) {
      int ka = s * 32 + kl;
      bf16x8 afr[4];
      if (s < 8) {
        #pragma unroll
        for (int mt = 0; mt < 4; ++mt) {
          int row = mt * 16 + l15;
          int off = (row << 9) + (ka << 1);
          off ^= (row & 7) << 4;
          afr[mt] = *(const bf16x8*)(smem + off);
        }
      } else {
        #pragma unroll
        for (int mt = 0; mt < 4; ++mt) afr[mt] = xr[mt][s - 8];
      }
      bf16x8 bfr[2];
      #pragma unroll
      for (int nt = 0; nt < 2; ++nt) {
        int jg = h * 128 + wvid * 32 + nt * 16 + l15;
        bfr[nt] = *(const bf16x8*)(wm + (size_t)jg * 512 + ka);
      }
      #pragma unroll
      for (int mt = 0; mt < 4; ++mt)
        #pragma unroll
        for (int nt = 0; nt < 2; ++nt)
          acc[mt][nt] = __builtin_amdgcn_mfma_f32_16x16x32_bf16(afr[mt], bfr[nt], acc[mt][nt], 0, 0, 0);
    }
  };

  auto store_rm = [&](f32x4 (&acc)[4][2], char* base, const float* bias, int h) {
    #pragma unroll
    for (int nt = 0; nt < 2; ++nt) {
      int col = wvid * 32 + nt * 16 + l15;
      float bi = bias[h * 128 + col];
      #pragma unroll
      for (int mt = 0; mt < 4; ++mt)
        #pragma unroll
        for (int rg = 0; rg < 4; ++rg) {
          int row = mt * 16 + rbase + rg;
          int off = (row << 8) + (col << 1);
          off ^= (row & 7) << 4;
          *(unsigned short*)(base + off) = f2b(acc[mt][nt][rg] + bi);
        }
    }
  };

  unsigned short* sl = slab + (size_t)blk * 32768;

  for (int h = 0; h < 4; ++h) {
    {
      f32x4 acc[4][2];
      gemm_r(wbf + 0 * 262144, h, acc);
      store_rm(acc, qb, bq, h);
      gemm_r(wbf + 1 * 262144, h, acc);
      store_rm(acc, kb, bk, h);
    }
    __syncthreads();
    f32x4 vacc[4][2];
    {
      f32x4 sacc[4];
      #pragma unroll
      for (int nt = 0; nt < 4; ++nt) sacc[nt] = (f32x4){0.f, 0.f, 0.f, 0.f};
      #pragma unroll
      for (int kk = 0; kk < 128; kk += 32) {
        int ka = kk + kl;
        int row = wvid * 16 + l15;
        int off = (row << 8) + (ka << 1); off ^= (row & 7) << 4;
        bf16x8 afr = *(const bf16x8*)(qb + off);
        #pragma unroll
        for (int nt = 0; nt < 4; ++nt) {
          int jr = nt * 16 + l15;
          int o2 = (jr << 8) + (ka << 1); o2 ^= (jr & 7) << 4;
          bf16x8 bfr = *(const bf16x8*)(kb + o2);
          sacc[nt] = __builtin_amdgcn_mfma_f32_16x16x32_bf16(afr, bfr, sacc[nt], 0, 0, 0);
        }
      }
      #pragma unroll
      for (int rg = 0; rg < 4; ++rg) {
        float m = -3.0e38f;
        #pragma unroll
        for (int nt = 0; nt < 4; ++nt) m = fmaxf(m, sacc[nt][rg]);
        #pragma unroll
        for (int dd = 1; dd < 16; dd <<= 1) m = fmaxf(m, __shfl_xor(m, dd, 64));
        float s = 0.f, e[4];
        #pragma unroll
        for (int nt = 0; nt < 4; ++nt) { e[nt] = __expf((sacc[nt][rg] - m) * SCALE); s += e[nt]; }
        #pragma unroll
        for (int dd = 1; dd < 16; dd <<= 1) s += __shfl_xor(s, dd, 64);
        float inv = 1.f / s;
        int row = wvid * 16 + rbase + rg;
        #pragma unroll
        for (int nt = 0; nt < 4; ++nt) {
          int col = nt * 16 + l15;
          int off = (row << 7) + (col << 1); off ^= (row & 7) << 4;
          *(unsigned short*)(pb + off) = f2b(e[nt] * inv);
        }
      }
      gemm_r(wbf + 2 * 262144, h, vacc);
    }
    __syncthreads();
    {
      #pragma unroll
      for (int nt = 0; nt < 2; ++nt) {
        int d = wvid * 32 + nt * 16 + l15;
        float bi = bv[h * 128 + d];
        #pragma unroll
        for (int mt = 0; mt < 4; ++mt) {
          int j0 = mt * 16 + rbase;
          u16x4 pk;
          #pragma unroll
          for (int rg = 0; rg < 4; ++rg) pk[rg] = f2b(vacc[mt][nt][rg] + bi);
          int off = (d << 7) + (j0 << 1); off ^= (d & 7) << 4;
          *(u16x4*)(kb + off) = pk;
        }
      }
    }
    __syncthreads();
    {
      f32x4 pacc[4][2];
      #pragma unroll
      for (int mt = 0; mt < 4; ++mt)
        #pragma unroll
        for (int nt = 0; nt < 2; ++nt) pacc[mt][nt] = (f32x4){0.f, 0.f, 0.f, 0.f};
      #pragma unroll
      for (int kk = 0; kk < 64; kk += 32) {
        int ka = kk + kl;
        bf16x8 afr[4];
        #pragma unroll
        for (int mt = 0; mt < 4; ++mt) {
          int row = mt * 16 + l15;
          int off = (row << 7) + (ka << 1); off ^= (row & 7) << 4;
          afr[mt] = *(const bf16x8*)(pb + off);
        }
        bf16x8 bfr[2];
        #pragma unroll
        for (int nt = 0; nt < 2; ++nt) {
          int d = wvid * 32 + nt * 16 + l15;
          int off = (d << 7) + (ka << 1); off ^= (d & 7) << 4;
          bfr[nt] = *(const bf16x8*)(kb + off);
        }
        #pragma unroll
        for (int mt = 0; mt < 4; ++mt)
          #pragma unroll
          for (int nt = 0; nt < 2; ++nt)
            pacc[mt][nt] = __builtin_amdgcn_mfma_f32_16x16x32_bf16(afr[mt], bfr[nt], pacc[mt][nt], 0, 0, 0);
      }
      #pragma unroll
      for (int nt = 0; nt < 2; ++nt) {
        int d = wvid * 32 + nt * 16 + l15;
        #pragma unroll
        for (int mt = 0; mt < 4; ++mt)
          #pragma unroll
          for (int rg = 0; rg < 4; ++rg) {
            int row = mt * 16 + rbase + rg;
            sl[row * 512 + h * 128 + d] = f2b(pacc[mt][nt][rg]);
          }
      }
    }
    __syncthreads();
  }
}

extern "C" void kernel_launch(void* const* d_in, const int* in_sizes, int n_in,
                              void* d_out, int out_size, void* d_ws, size_t ws_size,
                              hipStream_t stream) {
  const float* x  = (const float*)d_in[0];
  const float* Wq = (const float*)d_in[2];
  const float* bq = (const float*)d_in[3];
  const float* Wk = (const float*)d_in[4];
  const float* bk = (const float*)d_in[5];
  const float* Wv = (const float*)d_in[6];
  const float* bv = (const float*)d_in[7];
  const float* Wo = (const float*)d_in[8];
  const float* bo = (const float*)d_in[9];
  unsigned short* wbf = (unsigned short*)d_ws;

  cvt_weights<<<1024, 256, 0, stream>>>(Wq, Wk, Wv, Wo, wbf);

  const size_t need_full = (WOFF + 3 * SLABE) * 2;  // ~354 MB (known to fit)
  if (ws_size >= need_full) {
    unsigned short* qs  = wbf + WOFF;
    unsigned short* ks  = qs + SLABE;
    unsigned short* xs  = ks + SLABE;
    unsigned short* vst = (unsigned short*)d_out;   // d_out as V scratch
    xcvt<<<NBLK, 256, 0, stream>>>(x, xs);
    qkv_gemm<<<NBLK, 256, 0, stream>>>(xs, wbf, bq, bk, bv, qs, ks, vst);
    attn2<<<dim3(NBLK, 4), 256, 0, stream>>>(qs, ks, vst);
    proj_o<<<NBLK, 256, 0, stream>>>(qs, wbf + 3 * 262144, bo, (float*)d_out);
  } else {
    // tier 2: proven round-7 path (works from 119 MB ws)
    unsigned short* slab = wbf + WOFF;
    qkv_attn<<<NBLK, 256, 0, stream>>>(x, wbf, bq, bk, bv, slab);
    proj_o<<<NBLK, 256, 0, stream>>>(slab, wbf + 3 * 262144, bo, (float*)d_out);
  }
}

// Round 12
// 751.639 us; speedup vs baseline: 1.3122x; 1.3122x over previous
//
#include <hip/hip_runtime.h>
#include <hip/hip_bf16.h>

using bf16x8 = __attribute__((ext_vector_type(8))) short;
using f32x4  = __attribute__((ext_vector_type(4))) float;
using u16x4  = __attribute__((ext_vector_type(4))) unsigned short;

constexpr int Ht = 60, Wt = 108, C = 512;
constexpr int GWt = 14, NWIN = 112, NTOK = Ht * Wt, BT = 16;
constexpr int NBLK = BT * NWIN;                    // 1792 windows
constexpr int MROWS = BT * NTOK;                   // 103680 = 810*128
constexpr float SCALE = 0.08838834764831845f;      // 1/sqrt(128)
constexpr size_t WOFF   = 4 * 262144;              // weights elems (bf16)
constexpr size_t SLAB2E = (size_t)MROWS * 512;     // token-order slab elems
constexpr size_t SLABE  = (size_t)NBLK * 64 * 512; // window-order slab (tier2)

__device__ __forceinline__ unsigned short f2b(float f) {   // f32 -> bf16 RNE
  union { float f; unsigned u; } v; v.f = f;
  unsigned r = v.u + 0x7fffu + ((v.u >> 16) & 1u);
  return (unsigned short)(r >> 16);
}
__device__ __forceinline__ bf16x8 cvt8(float4 a, float4 b) {
  union { bf16x8 v; __hip_bfloat162 h[4]; } u;
  u.h[0] = __float22bfloat162_rn(make_float2(a.x, a.y));
  u.h[1] = __float22bfloat162_rn(make_float2(a.z, a.w));
  u.h[2] = __float22bfloat162_rn(make_float2(b.x, b.y));
  u.h[3] = __float22bfloat162_rn(make_float2(b.z, b.w));
  return u.v;
}

__global__ void cvt_weights(const float* __restrict__ a, const float* __restrict__ b,
                            const float* __restrict__ c, const float* __restrict__ d,
                            unsigned short* __restrict__ dst) {
  int i = blockIdx.x * blockDim.x + threadIdx.x;
  int m  = i >> 16;
  int o4 = i & 65535;
  const float* src = (m == 0) ? a : (m == 1) ? b : (m == 2) ? c : d;
  float4 v = *(const float4*)(src + (size_t)o4 * 4);
  u16x4 o;
  o[0] = f2b(v.x); o[1] = f2b(v.y); o[2] = f2b(v.z); o[3] = f2b(v.w);
  *(u16x4*)(dst + (size_t)m * 262144 + (size_t)o4 * 4) = o;
}

// ===== K1: dense QKV GEMM, 128x128 tile, BK=32, double-buffered =============
// C[m] = x @ Wm^T. grid (810, 12): y -> matrix m=y>>2, col-block j0=(y&3)*128.
extern "C" __global__ __launch_bounds__(256, 2)
void qkv_big(const float* __restrict__ x,
             const unsigned short* __restrict__ wbf,
             const float* __restrict__ bq, const float* __restrict__ bk,
             const float* __restrict__ bv,
             unsigned short* __restrict__ qs,
             unsigned short* __restrict__ ks,
             unsigned short* __restrict__ vs)
{
  __shared__ short As[2][4096];   // [128][32] bf16, 8 KB each
  __shared__ short Bs[2][4096];

  const int tid   = threadIdx.x;
  const int wvid  = tid >> 6;
  const int lane  = tid & 63;
  const int l15   = lane & 15;
  const int kl    = (lane >> 4) << 3;
  const int rbase = (lane >> 4) << 2;

  const int t0 = blockIdx.x * 128;
  const int n  = blockIdx.y;
  const int m  = n >> 2;
  const int j0 = (n & 3) * 128;
  const unsigned short* wm = wbf + (size_t)m * 262144;
  const float* bias = (m == 0) ? bq : (m == 1) ? bk : bv;
  unsigned short* dst = (m == 0) ? qs : (m == 1) ? ks : vs;

  const int srow = tid >> 1, sh = tid & 1;   // staging: row, k-half (16 elems)
  auto loff = [](int row, int p) { return (row << 6) + ((p ^ ((row & 6) >> 1)) << 4); };

  // prologue: stage step 0 into buffer 0
  {
    const float* sa = x + (size_t)(t0 + srow) * 512 + sh * 16;
    float4 a0 = *(const float4*)(sa),     a1 = *(const float4*)(sa + 4);
    float4 a2 = *(const float4*)(sa + 8), a3 = *(const float4*)(sa + 12);
    *(bf16x8*)((char*)As[0] + loff(srow, sh * 2))     = cvt8(a0, a1);
    *(bf16x8*)((char*)As[0] + loff(srow, sh * 2 + 1)) = cvt8(a2, a3);
    const unsigned short* sb = wm + (size_t)(j0 + srow) * 512 + sh * 16;
    *(bf16x8*)((char*)Bs[0] + loff(srow, sh * 2))     = *(const bf16x8*)(sb);
    *(bf16x8*)((char*)Bs[0] + loff(srow, sh * 2 + 1)) = *(const bf16x8*)(sb + 8);
  }
  __syncthreads();

  f32x4 acc[4][4];
  #pragma unroll
  for (int mt = 0; mt < 4; ++mt)
    #pragma unroll
    for (int nt = 0; nt < 4; ++nt) acc[mt][nt] = (f32x4){0.f, 0.f, 0.f, 0.f};

  const int wr = (wvid >> 1) * 64, wc = (wvid & 1) * 64;
  int cur = 0;
  for (int s = 0; s < 16; ++s) {
    float4 pa0, pa1, pa2, pa3; bf16x8 pb0, pb1;
    if (s < 15) {                       // issue next-step loads early
      const float* sa = x + (size_t)(t0 + srow) * 512 + (s + 1) * 32 + sh * 16;
      pa0 = *(const float4*)(sa);     pa1 = *(const float4*)(sa + 4);
      pa2 = *(const float4*)(sa + 8); pa3 = *(const float4*)(sa + 12);
      const unsigned short* sb = wm + (size_t)(j0 + srow) * 512 + (s + 1) * 32 + sh * 16;
      pb0 = *(const bf16x8*)(sb); pb1 = *(const bf16x8*)(sb + 8);
    }
    bf16x8 afr[4], bfr[4];
    #pragma unroll
    for (int mt = 0; mt < 4; ++mt)
      afr[mt] = *(const bf16x8*)((char*)As[cur] + loff(wr + mt * 16 + l15, kl >> 3));
    #pragma unroll
    for (int nt = 0; nt < 4; ++nt)
      bfr[nt] = *(const bf16x8*)((char*)Bs[cur] + loff(wc + nt * 16 + l15, kl >> 3));
    #pragma unroll
    for (int mt = 0; mt < 4; ++mt)
      #pragma unroll
      for (int nt = 0; nt < 4; ++nt)
        acc[mt][nt] = __builtin_amdgcn_mfma_f32_16x16x32_bf16(afr[mt], bfr[nt], acc[mt][nt], 0, 0, 0);
    if (s < 15) {
      *(bf16x8*)((char*)As[cur ^ 1] + loff(srow, sh * 2))     = cvt8(pa0, pa1);
      *(bf16x8*)((char*)As[cur ^ 1] + loff(srow, sh * 2 + 1)) = cvt8(pa2, pa3);
      *(bf16x8*)((char*)Bs[cur ^ 1] + loff(srow, sh * 2))     = pb0;
      *(bf16x8*)((char*)Bs[cur ^ 1] + loff(srow, sh * 2 + 1)) = pb1;
      __syncthreads();
      cur ^= 1;
    }
  }

  // epilogue: bias + bf16 store (token-order row-major)
  #pragma unroll
  for (int nt = 0; nt < 4; ++nt) {
    int col = j0 + wc + nt * 16 + l15;
    float bi = bias[col];
    #pragma unroll
    for (int mt = 0; mt < 4; ++mt)
      #pragma unroll
      for (int rg = 0; rg < 4; ++rg) {
        int row = t0 + wr + mt * 16 + rbase + rg;
        dst[(size_t)row * 512 + col] = f2b(acc[mt][nt][rg] + bi);
      }
  }
}

// ===== K2: per-(window,head) attention over token-order slabs ===============
// Pad rows use bk/bv bias values. attn output aliases Q slab (disjoint).
extern "C" __global__ __launch_bounds__(256, 4)
void attn_tok(unsigned short* __restrict__ qs,      // in: Q; out: attn (alias)
              const unsigned short* __restrict__ ks,
              const unsigned short* __restrict__ vs,
              const float* __restrict__ bk, const float* __restrict__ bv)
{
  __shared__ char kbuf[16384];
  __shared__ char vtb[16384];
  __shared__ char pbf[8192];

  const int tid   = threadIdx.x;
  const int wvid  = tid >> 6;
  const int lane  = tid & 63;
  const int l15   = lane & 15;
  const int kl    = (lane >> 4) << 3;
  const int rbase = (lane >> 4) << 2;

  const int w   = blockIdx.x;
  const int h   = blockIdx.y;
  const int b   = w / NWIN;
  const int win = w - b * NWIN;
  const int wy  = win / GWt, wx = win - wy * GWt;
  const int bt0 = b * NTOK;

  auto rowtok = [&](int r, bool& val) {
    int gy = wy * 8 + (r >> 3), gx = wx * 8 + (r & 7);
    val = (gy < Ht) && (gx < Wt);
    return bt0 + gy * Wt + gx;
  };

  // ---- stage K [64][128] -> LDS swizzled; pad rows from bk ----
  #pragma unroll
  for (int it = 0; it < 4; ++it) {
    int f  = it * 256 + tid;
    int r  = f >> 4;
    int c8 = f & 15;
    bool val; int tok = rowtok(r, val);
    bf16x8 v;
    if (val) {
      v = *(const bf16x8*)(ks + (size_t)tok * 512 + h * 128 + c8 * 8);
    } else {
      #pragma unroll
      for (int e = 0; e < 8; ++e)
        v[e] = (short)f2b(bk[h * 128 + c8 * 8 + e]);
    }
    int off = (r << 8) + (c8 << 4); off ^= (r & 7) << 4;
    *(bf16x8*)(kbuf + off) = v;
  }
  // ---- stage V transposed [128 d][64 tok]; pad rows from bv ----
  {
    int tok_r = tid & 63;
    int dg    = tid >> 6;
    bool val; int tok = rowtok(tok_r, val);
    bf16x8 vv[4];
    #pragma unroll
    for (int s4 = 0; s4 < 4; ++s4) {
      if (val) {
        vv[s4] = *(const bf16x8*)(vs + (size_t)tok * 512 + h * 128 + dg * 32 + s4 * 8);
      } else {
        #pragma unroll
        for (int e = 0; e < 8; ++e)
          vv[s4][e] = (short)f2b(bv[h * 128 + dg * 32 + s4 * 8 + e]);
      }
    }
    #pragma unroll
    for (int s4 = 0; s4 < 4; ++s4)
      #pragma unroll
      for (int e = 0; e < 8; ++e) {
        int d = dg * 32 + s4 * 8 + e;
        int off = (d << 7) + (tok_r << 1); off ^= (d & 7) << 4;
        *(unsigned short*)(vtb + off) = (unsigned short)vv[s4][e];
      }
  }
  __syncthreads();

  // ---- QK^T: wave owns 16 q-rows, Q direct from slab (pad -> finite dummy) --
  int qr = wvid * 16 + l15;
  bool qval; int qtok = rowtok(qr, qval);
  const unsigned short* qrow = qs + (size_t)(qval ? qtok : bt0) * 512 + h * 128;

  f32x4 sacc[4];
  #pragma unroll
  for (int nt = 0; nt < 4; ++nt) sacc[nt] = (f32x4){0.f, 0.f, 0.f, 0.f};
  #pragma unroll
  for (int kk = 0; kk < 128; kk += 32) {
    int ka = kk + kl;
    bf16x8 afr = *(const bf16x8*)(qrow + ka);
    #pragma unroll
    for (int nt = 0; nt < 4; ++nt) {
      int jr = nt * 16 + l15;
      int o2 = (jr << 8) + (ka << 1); o2 ^= (jr & 7) << 4;
      bf16x8 bfr = *(const bf16x8*)(kbuf + o2);
      sacc[nt] = __builtin_amdgcn_mfma_f32_16x16x32_bf16(afr, bfr, sacc[nt], 0, 0, 0);
    }
  }
  // ---- softmax, P -> LDS ----
  #pragma unroll
  for (int rg = 0; rg < 4; ++rg) {
    float mx = -3.0e38f;
    #pragma unroll
    for (int nt = 0; nt < 4; ++nt) mx = fmaxf(mx, sacc[nt][rg]);
    #pragma unroll
    for (int dd = 1; dd < 16; dd <<= 1) mx = fmaxf(mx, __shfl_xor(mx, dd, 64));
    float s = 0.f, e[4];
    #pragma unroll
    for (int nt = 0; nt < 4; ++nt) { e[nt] = __expf((sacc[nt][rg] - mx) * SCALE); s += e[nt]; }
    #pragma unroll
    for (int dd = 1; dd < 16; dd <<= 1) s += __shfl_xor(s, dd, 64);
    float inv = 1.f / s;
    int row = wvid * 16 + rbase + rg;
    #pragma unroll
    for (int nt = 0; nt < 4; ++nt) {
      int col = nt * 16 + l15;
      int off = (row << 7) + (col << 1); off ^= (row & 7) << 4;
      *(unsigned short*)(pbf + off) = f2b(e[nt] * inv);
    }
  }
  __syncthreads();

  // ---- PV: 64 rows x wave's 32 d-cols, K=64 ----
  f32x4 pacc[4][2];
  #pragma unroll
  for (int mt = 0; mt < 4; ++mt)
    #pragma unroll
    for (int nt = 0; nt < 2; ++nt) pacc[mt][nt] = (f32x4){0.f, 0.f, 0.f, 0.f};
  #pragma unroll
  for (int kk = 0; kk < 64; kk += 32) {
    int ka = kk + kl;
    bf16x8 afr[4];
    #pragma unroll
    for (int mt = 0; mt < 4; ++mt) {
      int row = mt * 16 + l15;
      int off = (row << 7) + (ka << 1); off ^= (row & 7) << 4;
      afr[mt] = *(const bf16x8*)(pbf + off);
    }
    bf16x8 bfr[2];
    #pragma unroll
    for (int nt = 0; nt < 2; ++nt) {
      int d = wvid * 32 + nt * 16 + l15;
      int off = (d << 7) + (ka << 1); off ^= (d & 7) << 4;
      bfr[nt] = *(const bf16x8*)(vtb + off);
    }
    #pragma unroll
    for (int mt = 0; mt < 4; ++mt)
      #pragma unroll
      for (int nt = 0; nt < 2; ++nt)
        pacc[mt][nt] = __builtin_amdgcn_mfma_f32_16x16x32_bf16(afr[mt], bfr[nt], pacc[mt][nt], 0, 0, 0);
  }
  // ---- write attn over Q slab rows (valid tokens only) ----
  #pragma unroll
  for (int mt = 0; mt < 4; ++mt)
    #pragma unroll
    for (int rg = 0; rg < 4; ++rg) {
      int r = mt * 16 + rbase + rg;
      bool val; int tok = rowtok(r, val);
      if (val) {
        unsigned short* po = qs + (size_t)tok * 512 + h * 128;
        #pragma unroll
        for (int nt = 0; nt < 2; ++nt)
          po[wvid * 32 + nt * 16 + l15] = f2b(pacc[mt][nt][rg]);
      }
    }
}

// ===== K3: out = attn_slab @ Wo^T + bo (token-order, contiguous) ============
extern "C" __global__ __launch_bounds__(256, 2)
void proj_tok(const unsigned short* __restrict__ slab,
              const unsigned short* __restrict__ wo,
              const float* __restrict__ bo,
              float* __restrict__ out)
{
  __shared__ char smem[65536];
  const int tid   = threadIdx.x;
  const int wvid  = tid >> 6;
  const int lane  = tid & 63;
  const int l15   = lane & 15;
  const int kl    = (lane >> 4) << 3;
  const int rbase = (lane >> 4) << 2;
  const size_t row0 = (size_t)blockIdx.x * 64;

  for (int it = 0; it < 16; ++it) {
    int f  = it * 256 + tid;
    int r  = f >> 6;
    int c8 = f & 63;
    bf16x8 v = *(const bf16x8*)(slab + (row0 + r) * 512 + c8 * 8);
    int off = (r << 10) + (c8 << 4); off ^= (r & 7) << 4;
    *(bf16x8*)(smem + off) = v;
  }
  __syncthreads();

  for (int half = 0; half < 2; ++half) {
    f32x4 acc[4][4];
    #pragma unroll
    for (int mt = 0; mt < 4; ++mt)
      #pragma unroll
      for (int nt = 0; nt < 4; ++nt) acc[mt][nt] = (f32x4){0.f, 0.f, 0.f, 0.f};
    #pragma unroll 2
    for (int kk = 0; kk < 512; kk += 32) {
      int ka = kk + kl;
      bf16x8 afr[4];
      #pragma unroll
      for (int mt = 0; mt < 4; ++mt) {
        int row = mt * 16 + l15;
        int off = (row << 10) + (ka << 1); off ^= (row & 7) << 4;
        afr[mt] = *(const bf16x8*)(smem + off);
      }
      bf16x8 bfr[4];
      #pragma unroll
      for (int nt = 0; nt < 4; ++nt) {
        int j = wvid * 128 + half * 64 + nt * 16 + l15;
        bfr[nt] = *(const bf16x8*)(wo + (size_t)j * 512 + ka);
      }
      #pragma unroll
      for (int mt = 0; mt < 4; ++mt)
        #pragma unroll
        for (int nt = 0; nt < 4; ++nt)
          acc[mt][nt] = __builtin_amdgcn_mfma_f32_16x16x32_bf16(afr[mt], bfr[nt], acc[mt][nt], 0, 0, 0);
    }
    #pragma unroll
    for (int mt = 0; mt < 4; ++mt)
      #pragma unroll
      for (int rg = 0; rg < 4; ++rg) {
        float* po = out + (row0 + mt * 16 + rbase + rg) * 512;
        #pragma unroll
        for (int nt = 0; nt < 4; ++nt) {
          int j = wvid * 128 + half * 64 + nt * 16 + l15;
          po[j] = acc[mt][nt][rg] + bo[j];
        }
      }
  }
}

// ===== TIER 2 fallback: round-7 fused kernel + window-order proj ============
extern "C" __global__ __launch_bounds__(256, 1)
void qkv_attn(const float* __restrict__ x,
              const unsigned short* __restrict__ wbf,
              const float* __restrict__ bq, const float* __restrict__ bk,
              const float* __restrict__ bv,
              unsigned short* __restrict__ slab)
{
  __shared__ char smem[73728];
  char* qb = smem + 32768;
  char* kb = smem + 49152;
  char* pb = smem + 65536;

  const int tid   = threadIdx.x;
  const int wvid  = tid >> 6;
  const int lane  = tid & 63;
  const int l15   = lane & 15;
  const int kl    = (lane >> 4) << 3;
  const int rbase = (lane >> 4) << 2;

  const int blk = blockIdx.x;
  const int b   = blk / NWIN;
  const int w   = blk - b * NWIN;
  const int wy  = w / GWt, wx = w - wy * GWt;

  for (int it = 0; it < 32; ++it) {
    int f  = it * 256 + tid;
    int r  = f >> 7;
    int c4 = f & 127;
    int gy = wy * 8 + (r >> 3), gx = wx * 8 + (r & 7);
    float4 v = make_float4(0.f, 0.f, 0.f, 0.f);
    if (gy < Ht && gx < Wt)
      v = *(const float4*)(x + ((size_t)b * NTOK + gy * Wt + gx) * C + c4 * 4);
    u16x4 o;
    o[0] = f2b(v.x); o[1] = f2b(v.y); o[2] = f2b(v.z); o[3] = f2b(v.w);
    int lc  = c4 & 63;
    int off = (r << 9) + (lc << 3);
    off ^= (r & 7) << 4;
    off += (c4 >> 6) * 32768;
    *(u16x4*)(smem + off) = o;
  }
  __syncthreads();

  bf16x8 xr[4][8];
  #pragma unroll
  for (int mt = 0; mt < 4; ++mt) {
    int row = mt * 16 + l15;
    #pragma unroll
    for (int s = 0; s < 8; ++s) {
      int off = (row << 9) + ((s * 32 + kl) << 1);
      off ^= (row & 7) << 4;
      xr[mt][s] = *(const bf16x8*)(smem + 32768 + off);
    }
  }
  __syncthreads();

  auto gemm_r = [&](const unsigned short* wm, int h, f32x4 (&acc)[4][2]) {
    #pragma unroll
    for (int mt = 0; mt < 4; ++mt)
      #pragma unroll
      for (int nt = 0; nt < 2; ++nt) acc[mt][nt] = (f32x4){0.f, 0.f, 0.f, 0.f};
    #pragma unroll
    for (int s = 0; s < 16; ++s) {
      int ka = s * 32 + kl;
      bf16x8 afr[4];
      if (s < 8) {
        #pragma unroll
        for (int mt = 0; mt < 4; ++mt) {
          int row = mt * 16 + l15;
          int off = (row << 9) + (ka << 1);
          off ^= (row & 7) << 4;
          afr[mt] = *(const bf16x8*)(smem + off);
        }
      } else {
        #pragma unroll
        for (int mt = 0; mt < 4; ++mt) afr[mt] = xr[mt][s - 8];
      }
      bf16x8 bfr[2];
      #pragma unroll
      for (int nt = 0; nt < 2; ++nt) {
        int jg = h * 128 + wvid * 32 + nt * 16 + l15;
        bfr[nt] = *(const bf16x8*)(wm + (size_t)jg * 512 + ka);
      }
      #pragma unroll
      for (int mt = 0; mt < 4; ++mt)
        #pragma unroll
        for (int nt = 0; nt < 2; ++nt)
          acc[mt][nt] = __builtin_amdgcn_mfma_f32_16x16x32_bf16(afr[mt], bfr[nt], acc[mt][nt], 0, 0, 0);
    }
  };

  auto store_rm = [&](f32x4 (&acc)[4][2], char* base, const float* bias, int h) {
    #pragma unroll
    for (int nt = 0; nt < 2; ++nt) {
      int col = wvid * 32 + nt * 16 + l15;
      float bi = bias[h * 128 + col];
      #pragma unroll
      for (int mt = 0; mt < 4; ++mt)
        #pragma unroll
        for (int rg = 0; rg < 4; ++rg) {
          int row = mt * 16 + rbase + rg;
          int off = (row << 8) + (col << 1);
          off ^= (row & 7) << 4;
          *(unsigned short*)(base + off) = f2b(acc[mt][nt][rg] + bi);
        }
    }
  };

  unsigned short* sl = slab + (size_t)blk * 32768;

  for (int h = 0; h < 4; ++h) {
    {
      f32x4 acc[4][2];
      gemm_r(wbf + 0 * 262144, h, acc);
      store_rm(acc, qb, bq, h);
      gemm_r(wbf + 1 * 262144, h, acc);
      store_rm(acc, kb, bk, h);
    }
    __syncthreads();
    f32x4 vacc[4][2];
    {
      f32x4 sacc[4];
      #pragma unroll
      for (int nt = 0; nt < 4; ++nt) sacc[nt] = (f32x4){0.f, 0.f, 0.f, 0.f};
      #pragma unroll
      for (int kk = 0; kk < 128; kk += 32) {
        int ka = kk + kl;
        int row = wvid * 16 + l15;
        int off = (row << 8) + (ka << 1); off ^= (row & 7) << 4;
        bf16x8 afr = *(const bf16x8*)(qb + off);
        #pragma unroll
        for (int nt = 0; nt < 4; ++nt) {
          int jr = nt * 16 + l15;
          int o2 = (jr << 8) + (ka << 1); o2 ^= (jr & 7) << 4;
          bf16x8 bfr = *(const bf16x8*)(kb + o2);
          sacc[nt] = __builtin_amdgcn_mfma_f32_16x16x32_bf16(afr, bfr, sacc[nt], 0, 0, 0);
        }
      }
      #pragma unroll
      for (int rg = 0; rg < 4; ++rg) {
        float mx = -3.0e38f;
        #pragma unroll
        for (int nt = 0; nt < 4; ++nt) mx = fmaxf(mx, sacc[nt][rg]);
        #pragma unroll
        for (int dd = 1; dd < 16; dd <<= 1) mx = fmaxf(mx, __shfl_xor(mx, dd, 64));
        float s = 0.f, e[4];
        #pragma unroll
        for (int nt = 0; nt < 4; ++nt) { e[nt] = __expf((sacc[nt][rg] - mx) * SCALE); s += e[nt]; }
        #pragma unroll
        for (int dd = 1; dd < 16; dd <<= 1) s += __shfl_xor(s, dd, 64);
        float inv = 1.f / s;
        int row = wvid * 16 + rbase + rg;
        #pragma unroll
        for (int nt = 0; nt < 4; ++nt) {
          int col = nt * 16 + l15;
          int off = (row << 7) + (col << 1); off ^= (row & 7) << 4;
          *(unsigned short*)(pb + off) = f2b(e[nt] * inv);
        }
      }
      gemm_r(wbf + 2 * 262144, h, vacc);
    }
    __syncthreads();
    {
      #pragma unroll
      for (int nt = 0; nt < 2; ++nt) {
        int d = wvid * 32 + nt * 16 + l15;
        float bi = bv[h * 128 + d];
        #pragma unroll
        for (int mt = 0; mt < 4; ++mt) {
          int j0 = mt * 16 + rbase;
          u16x4 pk;
          #pragma unroll
          for (int rg = 0; rg < 4; ++rg) pk[rg] = f2b(vacc[mt][nt][rg] + bi);
          int off = (d << 7) + (j0 << 1); off ^= (d & 7) << 4;
          *(u16x4*)(kb + off) = pk;
        }
      }
    }
    __syncthreads();
    {
      f32x4 pacc[4][2];
      #pragma unroll
      for (int mt = 0; mt < 4; ++mt)
        #pragma unroll
        for (int nt = 0; nt < 2; ++nt) pacc[mt][nt] = (f32x4){0.f, 0.f, 0.f, 0.f};
      #pragma unroll
      for (int kk = 0; kk < 64; kk += 32) {
        int ka = kk + kl;
        bf16x8 afr[4];
        #pragma unroll
        for (int mt = 0; mt < 4; ++mt) {
          int row = mt * 16 + l15;
          int off = (row << 7) + (ka << 1); off ^= (row & 7) << 4;
          afr[mt] = *(const bf16x8*)(pb + off);
        }
        bf16x8 bfr[2];
        #pragma unroll
        for (int nt = 0; nt < 2; ++nt) {
          int d = wvid * 32 + nt * 16 + l15;
          int off = (d << 7) + (ka << 1); off ^= (d & 7) << 4;
          bfr[nt] = *(const bf16x8*)(kb + off);
        }
        #pragma unroll
        for (int mt = 0; mt < 4; ++mt)
          #pragma unroll
          for (int nt = 0; nt < 2; ++nt)
            pacc[mt][nt] = __builtin_amdgcn_mfma_f32_16x16x32_bf16(afr[mt], bfr[nt], pacc[mt][nt], 0, 0, 0);
      }
      #pragma unroll
      for (int nt = 0; nt < 2; ++nt) {
        int d = wvid * 32 + nt * 16 + l15;
        #pragma unroll
        for (int mt = 0; mt < 4; ++mt)
          #pragma unroll
          for (int rg = 0; rg < 4; ++rg) {
            int row = mt * 16 + rbase + rg;
            sl[row * 512 + h * 128 + d] = f2b(pacc[mt][nt][rg]);
          }
      }
    }
    __syncthreads();
  }
}

extern "C" __global__ __launch_bounds__(256, 2)
void proj_win(const unsigned short* __restrict__ slab,
              const unsigned short* __restrict__ wo,
              const float* __restrict__ bo,
              float* __restrict__ out)
{
  __shared__ char smem[65536];
  const int tid   = threadIdx.x;
  const int wvid  = tid >> 6;
  const int lane  = tid & 63;
  const int l15   = lane & 15;
  const int kl    = (lane >> 4) << 3;
  const int rbase = (lane >> 4) << 2;

  const int blk = blockIdx.x;
  const int b   = blk / NWIN;
  const int w   = blk - b * NWIN;
  const int wy  = w / GWt, wx = w - wy * GWt;

  const unsigned short* src = slab + (size_t)blk * 32768;
  for (int it = 0; it < 16; ++it) {
    int f  = it * 256 + tid;
    int r  = f >> 6;
    int c8 = f & 63;
    bf16x8 v = *(const bf16x8*)(src + r * 512 + c8 * 8);
    int off = (r << 10) + (c8 << 4);
    off ^= (r & 7) << 4;
    *(bf16x8*)(smem + off) = v;
  }
  __syncthreads();

  for (int half = 0; half < 2; ++half) {
    f32x4 acc[4][4];
    #pragma unroll
    for (int mt = 0; mt < 4; ++mt)
      #pragma unroll
      for (int nt = 0; nt < 4; ++nt) acc[mt][nt] = (f32x4){0.f, 0.f, 0.f, 0.f};
    #pragma unroll 2
    for (int kk = 0; kk < 512; kk += 32) {
      int ka = kk + kl;
      bf16x8 afr[4];
      #pragma unroll
      for (int mt = 0; mt < 4; ++mt) {
        int row = mt * 16 + l15;
        int off = (row << 10) + (ka << 1); off ^= (row & 7) << 4;
        afr[mt] = *(const bf16x8*)(smem + off);
      }
      bf16x8 bfr[4];
      #pragma unroll
      for (int nt = 0; nt < 4; ++nt) {
        int j = wvid * 128 + half * 64 + nt * 16 + l15;
        bfr[nt] = *(const bf16x8*)(wo + (size_t)j * 512 + ka);
      }
      #pragma unroll
      for (int mt = 0; mt < 4; ++mt)
        #pragma unroll
        for (int nt = 0; nt < 4; ++nt)
          acc[mt][nt] = __builtin_amdgcn_mfma_f32_16x16x32_bf16(afr[mt], bfr[nt], acc[mt][nt], 0, 0, 0);
    }
    #pragma unroll
    for (int mt = 0; mt < 4; ++mt)
      #pragma unroll
      for (int rg = 0; rg < 4; ++rg) {
        int r = mt * 16 + rbase + rg;
        int gy = wy * 8 + (r >> 3), gx = wx * 8 + (r & 7);
        if (gy < Ht && gx < Wt) {
          float* po = out + ((size_t)b * NTOK + gy * Wt + gx) * C;
          #pragma unroll
          for (int nt = 0; nt < 4; ++nt) {
            int j = wvid * 128 + half * 64 + nt * 16 + l15;
            po[j] = acc[mt][nt][rg] + bo[j];
          }
        }
      }
  }
}

extern "C" void kernel_launch(void* const* d_in, const int* in_sizes, int n_in,
                              void* d_out, int out_size, void* d_ws, size_t ws_size,
                              hipStream_t stream) {
  const float* x  = (const float*)d_in[0];
  const float* Wq = (const float*)d_in[2];
  const float* bq = (const float*)d_in[3];
  const float* Wk = (const float*)d_in[4];
  const float* bk = (const float*)d_in[5];
  const float* Wv = (const float*)d_in[6];
  const float* bv = (const float*)d_in[7];
  const float* Wo = (const float*)d_in[8];
  const float* bo = (const float*)d_in[9];
  unsigned short* wbf = (unsigned short*)d_ws;

  cvt_weights<<<1024, 256, 0, stream>>>(Wq, Wk, Wv, Wo, wbf);

  const size_t need_full = (WOFF + 3 * SLAB2E) * 2;   // ~320 MB
  const size_t need_r7   = (WOFF + SLABE) * 2;        // ~119 MB

  if (ws_size >= need_full) {
    unsigned short* qs = wbf + WOFF;
    unsigned short* ks = qs + SLAB2E;
    unsigned short* vs = ks + SLAB2E;
    qkv_big<<<dim3(MROWS / 128, 12), 256, 0, stream>>>(x, wbf, bq, bk, bv, qs, ks, vs);
    attn_tok<<<dim3(NBLK, 4), 256, 0, stream>>>(qs, ks, vs, bk, bv);
    proj_tok<<<MROWS / 64, 256, 0, stream>>>(qs, wbf + 3 * 262144, bo, (float*)d_out);
  } else if (ws_size >= need_r7) {
    unsigned short* slab = wbf + WOFF;
    qkv_attn<<<NBLK, 256, 0, stream>>>(x, wbf, bq, bk, bv, slab);
    proj_win<<<NBLK, 256, 0, stream>>>(slab, wbf + 3 * 262144, bo, (float*)d_out);
  }
}

// Round 13
// 534.485 us; speedup vs baseline: 1.8453x; 1.4063x over previous
//
#include <hip/hip_runtime.h>
#include <hip/hip_bf16.h>

using bf16x8 = __attribute__((ext_vector_type(8))) short;
using f32x4  = __attribute__((ext_vector_type(4))) float;
using u16x4  = __attribute__((ext_vector_type(4))) unsigned short;

constexpr int Ht = 60, Wt = 108, C = 512;
constexpr int GWt = 14, NWIN = 112, NTOK = Ht * Wt, BT = 16;
constexpr int NBLK = BT * NWIN;                    // 1792 windows
constexpr int MROWS = BT * NTOK;                   // 103680 = 810*128
constexpr float SCALE = 0.08838834764831845f;      // 1/sqrt(128)
constexpr size_t WOFF  = 4 * 262144;               // weights elems (bf16)
constexpr size_t QKVE  = (size_t)MROWS * 1536;     // fused slab elems
constexpr size_t SLABE = (size_t)NBLK * 64 * 512;  // tier-2 slab elems

typedef __attribute__((address_space(3))) void lds_void;
typedef const __attribute__((address_space(1))) void g_void;
__device__ __forceinline__ void g2lds16(const void* g, void* l) {
  __builtin_amdgcn_global_load_lds((g_void*)g, (lds_void*)l, 16, 0, 0);
}

__device__ __forceinline__ unsigned short f2b(float f) {   // f32 -> bf16 RNE
  union { float f; unsigned u; } v; v.f = f;
  unsigned r = v.u + 0x7fffu + ((v.u >> 16) & 1u);
  return (unsigned short)(r >> 16);
}
__device__ __forceinline__ bf16x8 cvt8(float4 a, float4 b) {
  union { bf16x8 v; __hip_bfloat162 h[4]; } u;
  u.h[0] = __float22bfloat162_rn(make_float2(a.x, a.y));
  u.h[1] = __float22bfloat162_rn(make_float2(a.z, a.w));
  u.h[2] = __float22bfloat162_rn(make_float2(b.x, b.y));
  u.h[3] = __float22bfloat162_rn(make_float2(b.z, b.w));
  return u.v;
}

__global__ void cvt_weights(const float* __restrict__ a, const float* __restrict__ b,
                            const float* __restrict__ c, const float* __restrict__ d,
                            unsigned short* __restrict__ dst) {
  int i = blockIdx.x * blockDim.x + threadIdx.x;
  int m  = i >> 16;
  int o4 = i & 65535;
  const float* src = (m == 0) ? a : (m == 1) ? b : (m == 2) ? c : d;
  float4 v = *(const float4*)(src + (size_t)o4 * 4);
  u16x4 o;
  o[0] = f2b(v.x); o[1] = f2b(v.y); o[2] = f2b(v.z); o[3] = f2b(v.w);
  *(u16x4*)(dst + (size_t)m * 262144 + (size_t)o4 * 4) = o;
}

// ===== K0: x f32 -> bf16 token-order (into d_out scratch) ===================
extern "C" __global__ void xcvt_tok(const float* __restrict__ x,
                                    unsigned short* __restrict__ xb) {
  size_t idx = ((size_t)blockIdx.x * 256 + threadIdx.x) * 8;
  float4 a = *(const float4*)(x + idx);
  float4 b = *(const float4*)(x + idx + 4);
  *(bf16x8*)(xb + idx) = cvt8(a, b);
}

// ===== K1: m97-style fused QKV GEMM: [103680x512] @ [1536x512]^T ============
// 128x128 tile, BK=64, global_load_lds w16, swizzled-source linear LDS.
extern "C" __global__ __launch_bounds__(256, 4)
void qkv_m97(const unsigned short* __restrict__ xb,   // [MROWS][512] bf16
             const unsigned short* __restrict__ wf,   // [1536][512] bf16 fused
             const float* __restrict__ bq, const float* __restrict__ bk,
             const float* __restrict__ bv,
             unsigned short* __restrict__ qkvs)       // [MROWS][1536] bf16
{
  __shared__ char As[16384];   // [128][64] bf16, phys chunk = logical ^ (row&7)
  __shared__ char Bs[16384];

  const int tid   = threadIdx.x;
  const int wvid  = tid >> 6;
  const int lane  = tid & 63;
  const int l15   = lane & 15;
  const int rbase = (lane >> 4) << 2;

  // XCD-bijective swizzle (9720 = 8*1215): XCD k gets contiguous works,
  // works ordered tile-major so the 12 col-blocks of a tile stay L2-hot.
  const int i    = blockIdx.x;
  const int work = (i & 7) * 1215 + (i >> 3);
  const int t0   = (work / 12) * 128;
  const int j0   = (work % 12) * 128;

  // staging: wave w, issue ii covers rows w*32+ii*8 .. +7 (1 KB LDS each)
  const int lr = lane >> 3;             // row-in-group 0..7
  const int lc = (lane & 7) ^ lr;       // pre-swizzled source chunk
  const unsigned short* gA = xb + (size_t)(t0 + wvid * 32 + lr) * 512 + lc * 8;
  const unsigned short* gB = wf + (size_t)(j0 + wvid * 32 + lr) * 512 + lc * 8;
  char* lA = As + wvid * 4096;
  char* lB = Bs + wvid * 4096;

  f32x4 acc[4][4];
  #pragma unroll
  for (int mt = 0; mt < 4; ++mt)
    #pragma unroll
    for (int nt = 0; nt < 4; ++nt) acc[mt][nt] = (f32x4){0.f, 0.f, 0.f, 0.f};

  const int wr = (wvid >> 1) * 64, wc = (wvid & 1) * 64;

  for (int kk = 0; kk < 512; kk += 64) {
    #pragma unroll
    for (int ii = 0; ii < 4; ++ii) {
      g2lds16(gA + (size_t)ii * 8 * 512 + kk, lA + ii * 1024);
      g2lds16(gB + (size_t)ii * 8 * 512 + kk, lB + ii * 1024);
    }
    __syncthreads();                    // drains vmcnt before barrier
    #pragma unroll
    for (int ks = 0; ks < 2; ++ks) {
      const int lchunk = ks * 4 + (lane >> 4);
      bf16x8 afr[4], bfr[4];
      #pragma unroll
      for (int mt = 0; mt < 4; ++mt) {
        int row = wr + mt * 16 + l15;
        afr[mt] = *(const bf16x8*)(As + row * 128 + ((lchunk ^ (row & 7)) << 4));
      }
      #pragma unroll
      for (int nt = 0; nt < 4; ++nt) {
        int col = wc + nt * 16 + l15;
        bfr[nt] = *(const bf16x8*)(Bs + col * 128 + ((lchunk ^ (col & 7)) << 4));
      }
      #pragma unroll
      for (int mt = 0; mt < 4; ++mt)
        #pragma unroll
        for (int nt = 0; nt < 4; ++nt)
          acc[mt][nt] = __builtin_amdgcn_mfma_f32_16x16x32_bf16(afr[mt], bfr[nt], acc[mt][nt], 0, 0, 0);
    }
    __syncthreads();
  }

  // epilogue: bias + bf16 store into fused slab
  const int mloc = j0 >> 9;             // block's matrix (uniform)
  const float* bias = (mloc == 0) ? bq : (mloc == 1) ? bk : bv;
  const int jb = j0 & 511;
  #pragma unroll
  for (int nt = 0; nt < 4; ++nt) {
    int col = wc + nt * 16 + l15;
    float bi = bias[jb + col];
    #pragma unroll
    for (int mt = 0; mt < 4; ++mt)
      #pragma unroll
      for (int rg = 0; rg < 4; ++rg) {
        int row = t0 + wr + mt * 16 + rbase + rg;
        qkvs[(size_t)row * 1536 + j0 + col] = f2b(acc[mt][nt][rg] + bi);
      }
  }
}

// ===== K2: per-(window,head) attention over fused slab ======================
extern "C" __global__ __launch_bounds__(256, 4)
void attn_tok(unsigned short* __restrict__ qkvs,    // Q cols aliased as attn out
              const float* __restrict__ bk, const float* __restrict__ bv)
{
  __shared__ char kbuf[16384];
  __shared__ char vtb[16384];
  __shared__ char pbf[8192];

  const int tid   = threadIdx.x;
  const int wvid  = tid >> 6;
  const int lane  = tid & 63;
  const int l15   = lane & 15;
  const int kl    = (lane >> 4) << 3;
  const int rbase = (lane >> 4) << 2;

  const int w   = blockIdx.x;
  const int h   = blockIdx.y;
  const int b   = w / NWIN;
  const int win = w - b * NWIN;
  const int wy  = win / GWt, wx = win - wy * GWt;
  const int bt0 = b * NTOK;

  auto rowtok = [&](int r, bool& val) {
    int gy = wy * 8 + (r >> 3), gx = wx * 8 + (r & 7);
    val = (gy < Ht) && (gx < Wt);
    return bt0 + gy * Wt + gx;
  };

  // stage K (component offset 512); pad rows from bk
  #pragma unroll
  for (int it = 0; it < 4; ++it) {
    int f  = it * 256 + tid;
    int r  = f >> 4;
    int c8 = f & 15;
    bool val; int tok = rowtok(r, val);
    bf16x8 v;
    if (val) {
      v = *(const bf16x8*)(qkvs + (size_t)tok * 1536 + 512 + h * 128 + c8 * 8);
    } else {
      #pragma unroll
      for (int e = 0; e < 8; ++e)
        v[e] = (short)f2b(bk[h * 128 + c8 * 8 + e]);
    }
    int off = (r << 8) + (c8 << 4); off ^= (r & 7) << 4;
    *(bf16x8*)(kbuf + off) = v;
  }
  // stage V transposed (component offset 1024); pad rows from bv
  {
    int tok_r = tid & 63;
    int dg    = tid >> 6;
    bool val; int tok = rowtok(tok_r, val);
    bf16x8 vv[4];
    #pragma unroll
    for (int s4 = 0; s4 < 4; ++s4) {
      if (val) {
        vv[s4] = *(const bf16x8*)(qkvs + (size_t)tok * 1536 + 1024 + h * 128 + dg * 32 + s4 * 8);
      } else {
        #pragma unroll
        for (int e = 0; e < 8; ++e)
          vv[s4][e] = (short)f2b(bv[h * 128 + dg * 32 + s4 * 8 + e]);
      }
    }
    #pragma unroll
    for (int s4 = 0; s4 < 4; ++s4)
      #pragma unroll
      for (int e = 0; e < 8; ++e) {
        int d = dg * 32 + s4 * 8 + e;
        int off = (d << 7) + (tok_r << 1); off ^= (d & 7) << 4;
        *(unsigned short*)(vtb + off) = (unsigned short)vv[s4][e];
      }
  }
  __syncthreads();

  // QK^T (Q direct from slab; pad q-rows use dummy valid row)
  int qr = wvid * 16 + l15;
  bool qval; int qtok = rowtok(qr, qval);
  const unsigned short* qrow = qkvs + (size_t)(qval ? qtok : bt0) * 1536 + h * 128;

  f32x4 sacc[4];
  #pragma unroll
  for (int nt = 0; nt < 4; ++nt) sacc[nt] = (f32x4){0.f, 0.f, 0.f, 0.f};
  #pragma unroll
  for (int kk = 0; kk < 128; kk += 32) {
    int ka = kk + kl;
    bf16x8 afr = *(const bf16x8*)(qrow + ka);
    #pragma unroll
    for (int nt = 0; nt < 4; ++nt) {
      int jr = nt * 16 + l15;
      int o2 = (jr << 8) + (ka << 1); o2 ^= (jr & 7) << 4;
      bf16x8 bfr = *(const bf16x8*)(kbuf + o2);
      sacc[nt] = __builtin_amdgcn_mfma_f32_16x16x32_bf16(afr, bfr, sacc[nt], 0, 0, 0);
    }
  }
  // softmax, P -> LDS
  #pragma unroll
  for (int rg = 0; rg < 4; ++rg) {
    float mx = -3.0e38f;
    #pragma unroll
    for (int nt = 0; nt < 4; ++nt) mx = fmaxf(mx, sacc[nt][rg]);
    #pragma unroll
    for (int dd = 1; dd < 16; dd <<= 1) mx = fmaxf(mx, __shfl_xor(mx, dd, 64));
    float s = 0.f, e[4];
    #pragma unroll
    for (int nt = 0; nt < 4; ++nt) { e[nt] = __expf((sacc[nt][rg] - mx) * SCALE); s += e[nt]; }
    #pragma unroll
    for (int dd = 1; dd < 16; dd <<= 1) s += __shfl_xor(s, dd, 64);
    float inv = 1.f / s;
    int row = wvid * 16 + rbase + rg;
    #pragma unroll
    for (int nt = 0; nt < 4; ++nt) {
      int col = nt * 16 + l15;
      int off = (row << 7) + (col << 1); off ^= (row & 7) << 4;
      *(unsigned short*)(pbf + off) = f2b(e[nt] * inv);
    }
  }
  __syncthreads();

  // PV
  f32x4 pacc[4][2];
  #pragma unroll
  for (int mt = 0; mt < 4; ++mt)
    #pragma unroll
    for (int nt = 0; nt < 2; ++nt) pacc[mt][nt] = (f32x4){0.f, 0.f, 0.f, 0.f};
  #pragma unroll
  for (int kk = 0; kk < 64; kk += 32) {
    int ka = kk + kl;
    bf16x8 afr[4];
    #pragma unroll
    for (int mt = 0; mt < 4; ++mt) {
      int row = mt * 16 + l15;
      int off = (row << 7) + (ka << 1); off ^= (row & 7) << 4;
      afr[mt] = *(const bf16x8*)(pbf + off);
    }
    bf16x8 bfr[2];
    #pragma unroll
    for (int nt = 0; nt < 2; ++nt) {
      int d = wvid * 32 + nt * 16 + l15;
      int off = (d << 7) + (ka << 1); off ^= (d & 7) << 4;
      bfr[nt] = *(const bf16x8*)(vtb + off);
    }
    #pragma unroll
    for (int mt = 0; mt < 4; ++mt)
      #pragma unroll
      for (int nt = 0; nt < 2; ++nt)
        pacc[mt][nt] = __builtin_amdgcn_mfma_f32_16x16x32_bf16(afr[mt], bfr[nt], pacc[mt][nt], 0, 0, 0);
  }
  // write attn over Q component (valid tokens only; disjoint (tok, head))
  #pragma unroll
  for (int mt = 0; mt < 4; ++mt)
    #pragma unroll
    for (int rg = 0; rg < 4; ++rg) {
      int r = mt * 16 + rbase + rg;
      bool val; int tok = rowtok(r, val);
      if (val) {
        unsigned short* po = qkvs + (size_t)tok * 1536 + h * 128;
        #pragma unroll
        for (int nt = 0; nt < 2; ++nt)
          po[wvid * 32 + nt * 16 + l15] = f2b(pacc[mt][nt][rg]);
      }
    }
}

// ===== K3: out = attn(Q cols of fused slab) @ Wo^T + bo =====================
extern "C" __global__ __launch_bounds__(256, 2)
void proj_tok(const unsigned short* __restrict__ qkvs,
              const unsigned short* __restrict__ wo,
              const float* __restrict__ bo,
              float* __restrict__ out)
{
  __shared__ char smem[65536];
  const int tid   = threadIdx.x;
  const int wvid  = tid >> 6;
  const int lane  = tid & 63;
  const int l15   = lane & 15;
  const int kl    = (lane >> 4) << 3;
  const int rbase = (lane >> 4) << 2;
  const size_t row0 = (size_t)blockIdx.x * 64;

  for (int it = 0; it < 16; ++it) {
    int f  = it * 256 + tid;
    int r  = f >> 6;
    int c8 = f & 63;
    bf16x8 v = *(const bf16x8*)(qkvs + (row0 + r) * 1536 + c8 * 8);
    int off = (r << 10) + (c8 << 4); off ^= (r & 7) << 4;
    *(bf16x8*)(smem + off) = v;
  }
  __syncthreads();

  for (int half = 0; half < 2; ++half) {
    f32x4 acc[4][4];
    #pragma unroll
    for (int mt = 0; mt < 4; ++mt)
      #pragma unroll
      for (int nt = 0; nt < 4; ++nt) acc[mt][nt] = (f32x4){0.f, 0.f, 0.f, 0.f};
    #pragma unroll 2
    for (int kk = 0; kk < 512; kk += 32) {
      int ka = kk + kl;
      bf16x8 afr[4];
      #pragma unroll
      for (int mt = 0; mt < 4; ++mt) {
        int row = mt * 16 + l15;
        int off = (row << 10) + (ka << 1); off ^= (row & 7) << 4;
        afr[mt] = *(const bf16x8*)(smem + off);
      }
      bf16x8 bfr[4];
      #pragma unroll
      for (int nt = 0; nt < 4; ++nt) {
        int j = wvid * 128 + half * 64 + nt * 16 + l15;
        bfr[nt] = *(const bf16x8*)(wo + (size_t)j * 512 + ka);
      }
      #pragma unroll
      for (int mt = 0; mt < 4; ++mt)
        #pragma unroll
        for (int nt = 0; nt < 4; ++nt)
          acc[mt][nt] = __builtin_amdgcn_mfma_f32_16x16x32_bf16(afr[mt], bfr[nt], acc[mt][nt], 0, 0, 0);
    }
    #pragma unroll
    for (int mt = 0; mt < 4; ++mt)
      #pragma unroll
      for (int rg = 0; rg < 4; ++rg) {
        float* po = out + (row0 + mt * 16 + rbase + rg) * 512;
        #pragma unroll
        for (int nt = 0; nt < 4; ++nt) {
          int j = wvid * 128 + half * 64 + nt * 16 + l15;
          po[j] = acc[mt][nt][rg] + bo[j];
        }
      }
  }
}

// ===== TIER 2 fallback: round-7 fused kernel + window-order proj ============
extern "C" __global__ __launch_bounds__(256, 1)
void qkv_attn(const float* __restrict__ x,
              const unsigned short* __restrict__ wbf,
              const float* __restrict__ bq, const float* __restrict__ bk,
              const float* __restrict__ bv,
              unsigned short* __restrict__ slab)
{
  __shared__ char smem[73728];
  char* qb = smem + 32768;
  char* kb = smem + 49152;
  char* pb = smem + 65536;

  const int tid   = threadIdx.x;
  const int wvid  = tid >> 6;
  const int lane  = tid & 63;
  const int l15   = lane & 15;
  const int kl    = (lane >> 4) << 3;
  const int rbase = (lane >> 4) << 2;

  const int blk = blockIdx.x;
  const int b   = blk / NWIN;
  const int w   = blk - b * NWIN;
  const int wy  = w / GWt, wx = w - wy * GWt;

  for (int it = 0; it < 32; ++it) {
    int f  = it * 256 + tid;
    int r  = f >> 7;
    int c4 = f & 127;
    int gy = wy * 8 + (r >> 3), gx = wx * 8 + (r & 7);
    float4 v = make_float4(0.f, 0.f, 0.f, 0.f);
    if (gy < Ht && gx < Wt)
      v = *(const float4*)(x + ((size_t)b * NTOK + gy * Wt + gx) * C + c4 * 4);
    u16x4 o;
    o[0] = f2b(v.x); o[1] = f2b(v.y); o[2] = f2b(v.z); o[3] = f2b(v.w);
    int lc  = c4 & 63;
    int off = (r << 9) + (lc << 3);
    off ^= (r & 7) << 4;
    off += (c4 >> 6) * 32768;
    *(u16x4*)(smem + off) = o;
  }
  __syncthreads();

  bf16x8 xr[4][8];
  #pragma unroll
  for (int mt = 0; mt < 4; ++mt) {
    int row = mt * 16 + l15;
    #pragma unroll
    for (int s = 0; s < 8; ++s) {
      int off = (row << 9) + ((s * 32 + kl) << 1);
      off ^= (row & 7) << 4;
      xr[mt][s] = *(const bf16x8*)(smem + 32768 + off);
    }
  }
  __syncthreads();

  auto gemm_r = [&](const unsigned short* wm, int h, f32x4 (&acc)[4][2]) {
    #pragma unroll
    for (int mt = 0; mt < 4; ++mt)
      #pragma unroll
      for (int nt = 0; nt < 2; ++nt) acc[mt][nt] = (f32x4){0.f, 0.f, 0.f, 0.f};
    #pragma unroll
    for (int s = 0; s < 16; ++s) {
      int ka = s * 32 + kl;
      bf16x8 afr[4];
      if (s < 8) {
        #pragma unroll
        for (int mt = 0; mt < 4; ++mt) {
          int row = mt * 16 + l15;
          int off = (row << 9) + (ka << 1);
          off ^= (row & 7) << 4;
          afr[mt] = *(const bf16x8*)(smem + off);
        }
      } else {
        #pragma unroll
        for (int mt = 0; mt < 4; ++mt) afr[mt] = xr[mt][s - 8];
      }
      bf16x8 bfr[2];
      #pragma unroll
      for (int nt = 0; nt < 2; ++nt) {
        int jg = h * 128 + wvid * 32 + nt * 16 + l15;
        bfr[nt] = *(const bf16x8*)(wm + (size_t)jg * 512 + ka);
      }
      #pragma unroll
      for (int mt = 0; mt < 4; ++mt)
        #pragma unroll
        for (int nt = 0; nt < 2; ++nt)
          acc[mt][nt] = __builtin_amdgcn_mfma_f32_16x16x32_bf16(afr[mt], bfr[nt], acc[mt][nt], 0, 0, 0);
    }
  };

  auto store_rm = [&](f32x4 (&acc)[4][2], char* base, const float* bias, int h) {
    #pragma unroll
    for (int nt = 0; nt < 2; ++nt) {
      int col = wvid * 32 + nt * 16 + l15;
      float bi = bias[h * 128 + col];
      #pragma unroll
      for (int mt = 0; mt < 4; ++mt)
        #pragma unroll
        for (int rg = 0; rg < 4; ++rg) {
          int row = mt * 16 + rbase + rg;
          int off = (row << 8) + (col << 1);
          off ^= (row & 7) << 4;
          *(unsigned short*)(base + off) = f2b(acc[mt][nt][rg] + bi);
        }
    }
  };

  unsigned short* sl = slab + (size_t)blk * 32768;

  for (int h = 0; h < 4; ++h) {
    {
      f32x4 acc[4][2];
      gemm_r(wbf + 0 * 262144, h, acc);
      store_rm(acc, qb, bq, h);
      gemm_r(wbf + 1 * 262144, h, acc);
      store_rm(acc, kb, bk, h);
    }
    __syncthreads();
    f32x4 vacc[4][2];
    {
      f32x4 sacc[4];
      #pragma unroll
      for (int nt = 0; nt < 4; ++nt) sacc[nt] = (f32x4){0.f, 0.f, 0.f, 0.f};
      #pragma unroll
      for (int kk = 0; kk < 128; kk += 32) {
        int ka = kk + kl;
        int row = wvid * 16 + l15;
        int off = (row << 8) + (ka << 1); off ^= (row & 7) << 4;
        bf16x8 afr = *(const bf16x8*)(qb + off);
        #pragma unroll
        for (int nt = 0; nt < 4; ++nt) {
          int jr = nt * 16 + l15;
          int o2 = (jr << 8) + (ka << 1); o2 ^= (jr & 7) << 4;
          bf16x8 bfr = *(const bf16x8*)(kb + o2);
          sacc[nt] = __builtin_amdgcn_mfma_f32_16x16x32_bf16(afr, bfr, sacc[nt], 0, 0, 0);
        }
      }
      #pragma unroll
      for (int rg = 0; rg < 4; ++rg) {
        float mx = -3.0e38f;
        #pragma unroll
        for (int nt = 0; nt < 4; ++nt) mx = fmaxf(mx, sacc[nt][rg]);
        #pragma unroll
        for (int dd = 1; dd < 16; dd <<= 1) mx = fmaxf(mx, __shfl_xor(mx, dd, 64));
        float s = 0.f, e[4];
        #pragma unroll
        for (int nt = 0; nt < 4; ++nt) { e[nt] = __expf((sacc[nt][rg] - mx) * SCALE); s += e[nt]; }
        #pragma unroll
        for (int dd = 1; dd < 16; dd <<= 1) s += __shfl_xor(s, dd, 64);
        float inv = 1.f / s;
        int row = wvid * 16 + rbase + rg;
        #pragma unroll
        for (int nt = 0; nt < 4; ++nt) {
          int col = nt * 16 + l15;
          int off = (row << 7) + (col << 1); off ^= (row & 7) << 4;
          *(unsigned short*)(pb + off) = f2b(e[nt] * inv);
        }
      }
      gemm_r(wbf + 2 * 262144, h, vacc);
    }
    __syncthreads();
    {
      #pragma unroll
      for (int nt = 0; nt < 2; ++nt) {
        int d = wvid * 32 + nt * 16 + l15;
        float bi = bv[h * 128 + d];
        #pragma unroll
        for (int mt = 0; mt < 4; ++mt) {
          int j0 = mt * 16 + rbase;
          u16x4 pk;
          #pragma unroll
          for (int rg = 0; rg < 4; ++rg) pk[rg] = f2b(vacc[mt][nt][rg] + bi);
          int off = (d << 7) + (j0 << 1); off ^= (d & 7) << 4;
          *(u16x4*)(kb + off) = pk;
        }
      }
    }
    __syncthreads();
    {
      f32x4 pacc[4][2];
      #pragma unroll
      for (int mt = 0; mt < 4; ++mt)
        #pragma unroll
        for (int nt = 0; nt < 2; ++nt) pacc[mt][nt] = (f32x4){0.f, 0.f, 0.f, 0.f};
      #pragma unroll
      for (int kk = 0; kk < 64; kk += 32) {
        int ka = kk + kl;
        bf16x8 afr[4];
        #pragma unroll
        for (int mt = 0; mt < 4; ++mt) {
          int row = mt * 16 + l15;
          int off = (row << 7) + (ka << 1); off ^= (row & 7) << 4;
          afr[mt] = *(const bf16x8*)(pb + off);
        }
        bf16x8 bfr[2];
        #pragma unroll
        for (int nt = 0; nt < 2; ++nt) {
          int d = wvid * 32 + nt * 16 + l15;
          int off = (d << 7) + (ka << 1); off ^= (d & 7) << 4;
          bfr[nt] = *(const bf16x8*)(kb + off);
        }
        #pragma unroll
        for (int mt = 0; mt < 4; ++mt)
          #pragma unroll
          for (int nt = 0; nt < 2; ++nt)
            pacc[mt][nt] = __builtin_amdgcn_mfma_f32_16x16x32_bf16(afr[mt], bfr[nt], pacc[mt][nt], 0, 0, 0);
      }
      #pragma unroll
      for (int nt = 0; nt < 2; ++nt) {
        int d = wvid * 32 + nt * 16 + l15;
        #pragma unroll
        for (int mt = 0; mt < 4; ++mt)
          #pragma unroll
          for (int rg = 0; rg < 4; ++rg) {
            int row = mt * 16 + rbase + rg;
            sl[row * 512 + h * 128 + d] = f2b(pacc[mt][nt][rg]);
          }
      }
    }
    __syncthreads();
  }
}

extern "C" __global__ __launch_bounds__(256, 2)
void proj_win(const unsigned short* __restrict__ slab,
              const unsigned short* __restrict__ wo,
              const float* __restrict__ bo,
              float* __restrict__ out)
{
  __shared__ char smem[65536];
  const int tid   = threadIdx.x;
  const int wvid  = tid >> 6;
  const int lane  = tid & 63;
  const int l15   = lane & 15;
  const int kl    = (lane >> 4) << 3;
  const int rbase = (lane >> 4) << 2;

  const int blk = blockIdx.x;
  const int b   = blk / NWIN;
  const int w   = blk - b * NWIN;
  const int wy  = w / GWt, wx = w - wy * GWt;

  const unsigned short* src = slab + (size_t)blk * 32768;
  for (int it = 0; it < 16; ++it) {
    int f  = it * 256 + tid;
    int r  = f >> 6;
    int c8 = f & 63;
    bf16x8 v = *(const bf16x8*)(src + r * 512 + c8 * 8);
    int off = (r << 10) + (c8 << 4);
    off ^= (r & 7) << 4;
    *(bf16x8*)(smem + off) = v;
  }
  __syncthreads();

  for (int half = 0; half < 2; ++half) {
    f32x4 acc[4][4];
    #pragma unroll
    for (int mt = 0; mt < 4; ++mt)
      #pragma unroll
      for (int nt = 0; nt < 4; ++nt) acc[mt][nt] = (f32x4){0.f, 0.f, 0.f, 0.f};
    #pragma unroll 2
    for (int kk = 0; kk < 512; kk += 32) {
      int ka = kk + kl;
      bf16x8 afr[4];
      #pragma unroll
      for (int mt = 0; mt < 4; ++mt) {
        int row = mt * 16 + l15;
        int off = (row << 10) + (ka << 1); off ^= (row & 7) << 4;
        afr[mt] = *(const bf16x8*)(smem + off);
      }
      bf16x8 bfr[4];
      #pragma unroll
      for (int nt = 0; nt < 4; ++nt) {
        int j = wvid * 128 + half * 64 + nt * 16 + l15;
        bfr[nt] = *(const bf16x8*)(wo + (size_t)j * 512 + ka);
      }
      #pragma unroll
      for (int mt = 0; mt < 4; ++mt)
        #pragma unroll
        for (int nt = 0; nt < 4; ++nt)
          acc[mt][nt] = __builtin_amdgcn_mfma_f32_16x16x32_bf16(afr[mt], bfr[nt], acc[mt][nt], 0, 0, 0);
    }
    #pragma unroll
    for (int mt = 0; mt < 4; ++mt)
      #pragma unroll
      for (int rg = 0; rg < 4; ++rg) {
        int r = mt * 16 + rbase + rg;
        int gy = wy * 8 + (r >> 3), gx = wx * 8 + (r & 7);
        if (gy < Ht && gx < Wt) {
          float* po = out + ((size_t)b * NTOK + gy * Wt + gx) * C;
          #pragma unroll
          for (int nt = 0; nt < 4; ++nt) {
            int j = wvid * 128 + half * 64 + nt * 16 + l15;
            po[j] = acc[mt][nt][rg] + bo[j];
          }
        }
      }
  }
}

extern "C" void kernel_launch(void* const* d_in, const int* in_sizes, int n_in,
                              void* d_out, int out_size, void* d_ws, size_t ws_size,
                              hipStream_t stream) {
  const float* x  = (const float*)d_in[0];
  const float* Wq = (const float*)d_in[2];
  const float* bq = (const float*)d_in[3];
  const float* Wk = (const float*)d_in[4];
  const float* bk = (const float*)d_in[5];
  const float* Wv = (const float*)d_in[6];
  const float* bv = (const float*)d_in[7];
  const float* Wo = (const float*)d_in[8];
  const float* bo = (const float*)d_in[9];
  unsigned short* wbf = (unsigned short*)d_ws;

  cvt_weights<<<1024, 256, 0, stream>>>(Wq, Wk, Wv, Wo, wbf);

  const size_t need_full = (WOFF + QKVE) * 2;     // ~321 MB
  const size_t need_r7   = (WOFF + SLABE) * 2;    // ~119 MB

  if (ws_size >= need_full) {
    unsigned short* qkvs = wbf + WOFF;
    unsigned short* xb   = (unsigned short*)d_out;   // d_out as bf16-x scratch
    xcvt_tok<<<MROWS * 512 / 2048, 256, 0, stream>>>(x, xb);
    qkv_m97<<<9720, 256, 0, stream>>>(xb, wbf, bq, bk, bv, qkvs);
    attn_tok<<<dim3(NBLK, 4), 256, 0, stream>>>(qkvs, bk, bv);
    proj_tok<<<MROWS / 64, 256, 0, stream>>>(qkvs, wbf + 3 * 262144, bo, (float*)d_out);
  } else if (ws_size >= need_r7) {
    unsigned short* slab = wbf + WOFF;
    qkv_attn<<<NBLK, 256, 0, stream>>>(x, wbf, bq, bk, bv, slab);
    proj_win<<<NBLK, 256, 0, stream>>>(slab, wbf + 3 * 262144, bo, (float*)d_out);
  }
}

// Round 14
// 497.472 us; speedup vs baseline: 1.9826x; 1.0744x over previous
//
#include <hip/hip_runtime.h>
#include <hip/hip_bf16.h>

using bf16x8 = __attribute__((ext_vector_type(8))) short;
using f32x4  = __attribute__((ext_vector_type(4))) float;
using u16x4  = __attribute__((ext_vector_type(4))) unsigned short;

constexpr int Ht = 60, Wt = 108, C = 512;
constexpr int GWt = 14, NWIN = 112, NTOK = Ht * Wt, BT = 16;
constexpr int NBLK = BT * NWIN;                    // 1792 windows
constexpr int MROWS = BT * NTOK;                   // 103680 = 810*128
constexpr float SCALE = 0.08838834764831845f;      // 1/sqrt(128)
constexpr size_t WOFF  = 4 * 262144;               // weights elems (bf16)
constexpr size_t QKVE  = (size_t)MROWS * 1536;     // fused slab elems
constexpr size_t SLABE = (size_t)NBLK * 64 * 512;  // tier-2 slab elems

typedef __attribute__((address_space(3))) void lds_void;
typedef const __attribute__((address_space(1))) void g_void;
__device__ __forceinline__ void g2lds16(const void* g, void* l) {
  __builtin_amdgcn_global_load_lds((g_void*)g, (lds_void*)l, 16, 0, 0);
}

__device__ __forceinline__ unsigned short f2b(float f) {   // f32 -> bf16 RNE
  union { float f; unsigned u; } v; v.f = f;
  unsigned r = v.u + 0x7fffu + ((v.u >> 16) & 1u);
  return (unsigned short)(r >> 16);
}
__device__ __forceinline__ bf16x8 cvt8(float4 a, float4 b) {
  union { bf16x8 v; __hip_bfloat162 h[4]; } u;
  u.h[0] = __float22bfloat162_rn(make_float2(a.x, a.y));
  u.h[1] = __float22bfloat162_rn(make_float2(a.z, a.w));
  u.h[2] = __float22bfloat162_rn(make_float2(b.x, b.y));
  u.h[3] = __float22bfloat162_rn(make_float2(b.z, b.w));
  return u.v;
}

__global__ void cvt_weights(const float* __restrict__ a, const float* __restrict__ b,
                            const float* __restrict__ c, const float* __restrict__ d,
                            unsigned short* __restrict__ dst) {
  int i = blockIdx.x * blockDim.x + threadIdx.x;
  int m  = i >> 16;
  int o4 = i & 65535;
  const float* src = (m == 0) ? a : (m == 1) ? b : (m == 2) ? c : d;
  float4 v = *(const float4*)(src + (size_t)o4 * 4);
  u16x4 o;
  o[0] = f2b(v.x); o[1] = f2b(v.y); o[2] = f2b(v.z); o[3] = f2b(v.w);
  *(u16x4*)(dst + (size_t)m * 262144 + (size_t)o4 * 4) = o;
}

// ===== K0: x f32 -> bf16 token-order (into d_out scratch) ===================
extern "C" __global__ void xcvt_tok(const float* __restrict__ x,
                                    unsigned short* __restrict__ xb) {
  size_t idx = ((size_t)blockIdx.x * 256 + threadIdx.x) * 8;
  float4 a = *(const float4*)(x + idx);
  float4 b = *(const float4*)(x + idx + 4);
  *(bf16x8*)(xb + idx) = cvt8(a, b);
}

// ===== K1: m97-style fused QKV GEMM: [103680x512] @ [1536x512]^T ============
extern "C" __global__ __launch_bounds__(256, 4)
void qkv_m97(const unsigned short* __restrict__ xb,   // [MROWS][512] bf16
             const unsigned short* __restrict__ wf,   // [1536][512] bf16 fused
             const float* __restrict__ bq, const float* __restrict__ bk,
             const float* __restrict__ bv,
             unsigned short* __restrict__ qkvs)       // [MROWS][1536] bf16
{
  __shared__ char As[16384];   // [128][64] bf16, phys chunk = logical ^ (row&7)
  __shared__ char Bs[16384];

  const int tid   = threadIdx.x;
  const int wvid  = tid >> 6;
  const int lane  = tid & 63;
  const int l15   = lane & 15;
  const int rbase = (lane >> 4) << 2;

  const int i    = blockIdx.x;
  const int work = (i & 7) * 1215 + (i >> 3);
  const int t0   = (work / 12) * 128;
  const int j0   = (work % 12) * 128;

  const int lr = lane >> 3;
  const int lc = (lane & 7) ^ lr;
  const unsigned short* gA = xb + (size_t)(t0 + wvid * 32 + lr) * 512 + lc * 8;
  const unsigned short* gB = wf + (size_t)(j0 + wvid * 32 + lr) * 512 + lc * 8;
  char* lA = As + wvid * 4096;
  char* lB = Bs + wvid * 4096;

  f32x4 acc[4][4];
  #pragma unroll
  for (int mt = 0; mt < 4; ++mt)
    #pragma unroll
    for (int nt = 0; nt < 4; ++nt) acc[mt][nt] = (f32x4){0.f, 0.f, 0.f, 0.f};

  const int wr = (wvid >> 1) * 64, wc = (wvid & 1) * 64;

  for (int kk = 0; kk < 512; kk += 64) {
    #pragma unroll
    for (int ii = 0; ii < 4; ++ii) {
      g2lds16(gA + (size_t)ii * 8 * 512 + kk, lA + ii * 1024);
      g2lds16(gB + (size_t)ii * 8 * 512 + kk, lB + ii * 1024);
    }
    __syncthreads();
    #pragma unroll
    for (int ks = 0; ks < 2; ++ks) {
      const int lchunk = ks * 4 + (lane >> 4);
      bf16x8 afr[4], bfr[4];
      #pragma unroll
      for (int mt = 0; mt < 4; ++mt) {
        int row = wr + mt * 16 + l15;
        afr[mt] = *(const bf16x8*)(As + row * 128 + ((lchunk ^ (row & 7)) << 4));
      }
      #pragma unroll
      for (int nt = 0; nt < 4; ++nt) {
        int col = wc + nt * 16 + l15;
        bfr[nt] = *(const bf16x8*)(Bs + col * 128 + ((lchunk ^ (col & 7)) << 4));
      }
      #pragma unroll
      for (int mt = 0; mt < 4; ++mt)
        #pragma unroll
        for (int nt = 0; nt < 4; ++nt)
          acc[mt][nt] = __builtin_amdgcn_mfma_f32_16x16x32_bf16(afr[mt], bfr[nt], acc[mt][nt], 0, 0, 0);
    }
    __syncthreads();
  }

  const int mloc = j0 >> 9;
  const float* bias = (mloc == 0) ? bq : (mloc == 1) ? bk : bv;
  const int jb = j0 & 511;
  #pragma unroll
  for (int nt = 0; nt < 4; ++nt) {
    int col = wc + nt * 16 + l15;
    float bi = bias[jb + col];
    #pragma unroll
    for (int mt = 0; mt < 4; ++mt)
      #pragma unroll
      for (int rg = 0; rg < 4; ++rg) {
        int row = t0 + wr + mt * 16 + rbase + rg;
        qkvs[(size_t)row * 1536 + j0 + col] = f2b(acc[mt][nt][rg] + bi);
      }
  }
}

// ===== K2: per-(window,head) attention. Q staged in LDS, buffer reused as P =
extern "C" __global__ __launch_bounds__(256, 3)
void attn_tok(unsigned short* __restrict__ qkvs,    // Q cols aliased as attn out
              const float* __restrict__ bk, const float* __restrict__ bv)
{
  __shared__ char kbuf[16384];
  __shared__ char vtb[16384];
  __shared__ char qpb[16384];          // Q [64][128] swz; reused as P [64][64]

  const int tid   = threadIdx.x;
  const int wvid  = tid >> 6;
  const int lane  = tid & 63;
  const int l15   = lane & 15;
  const int kl    = (lane >> 4) << 3;
  const int rbase = (lane >> 4) << 2;

  const int w   = blockIdx.x;
  const int h   = blockIdx.y;
  const int b   = w / NWIN;
  const int win = w - b * NWIN;
  const int wy  = win / GWt, wx = win - wy * GWt;
  const int bt0 = b * NTOK;

  auto rowtok = [&](int r, bool& val) {
    int gy = wy * 8 + (r >> 3), gx = wx * 8 + (r & 7);
    val = (gy < Ht) && (gx < Wt);
    return bt0 + gy * Wt + gx;
  };

  // stage Q (comp 0, pad rows = 0) and K (comp 512, pad rows = bk), swizzled
  #pragma unroll
  for (int it = 0; it < 4; ++it) {
    int f  = it * 256 + tid;
    int r  = f >> 4;
    int c8 = f & 15;
    bool val; int tok = rowtok(r, val);
    int off = (r << 8) + (c8 << 4); off ^= (r & 7) << 4;
    bf16x8 q, k;
    if (val) {
      const unsigned short* base = qkvs + (size_t)tok * 1536 + h * 128 + c8 * 8;
      q = *(const bf16x8*)(base);
      k = *(const bf16x8*)(base + 512);
    } else {
      #pragma unroll
      for (int e = 0; e < 8; ++e) {
        q[e] = 0;
        k[e] = (short)f2b(bk[h * 128 + c8 * 8 + e]);
      }
    }
    *(bf16x8*)(qpb + off) = q;
    *(bf16x8*)(kbuf + off) = k;
  }
  // stage V transposed (comp 1024); pad rows from bv
  {
    int tok_r = tid & 63;
    int dg    = tid >> 6;
    bool val; int tok = rowtok(tok_r, val);
    bf16x8 vv[4];
    #pragma unroll
    for (int s4 = 0; s4 < 4; ++s4) {
      if (val) {
        vv[s4] = *(const bf16x8*)(qkvs + (size_t)tok * 1536 + 1024 + h * 128 + dg * 32 + s4 * 8);
      } else {
        #pragma unroll
        for (int e = 0; e < 8; ++e)
          vv[s4][e] = (short)f2b(bv[h * 128 + dg * 32 + s4 * 8 + e]);
      }
    }
    #pragma unroll
    for (int s4 = 0; s4 < 4; ++s4)
      #pragma unroll
      for (int e = 0; e < 8; ++e) {
        int d = dg * 32 + s4 * 8 + e;
        int off = (d << 7) + (tok_r << 1); off ^= (d & 7) << 4;
        *(unsigned short*)(vtb + off) = (unsigned short)vv[s4][e];
      }
  }
  __syncthreads();

  // QK^T from LDS (wave owns 16 q-rows)
  f32x4 sacc[4];
  #pragma unroll
  for (int nt = 0; nt < 4; ++nt) sacc[nt] = (f32x4){0.f, 0.f, 0.f, 0.f};
  #pragma unroll
  for (int kk = 0; kk < 128; kk += 32) {
    int ka = kk + kl;
    int qr = wvid * 16 + l15;
    int qo = (qr << 8) + (ka << 1); qo ^= (qr & 7) << 4;
    bf16x8 afr = *(const bf16x8*)(qpb + qo);
    #pragma unroll
    for (int nt = 0; nt < 4; ++nt) {
      int jr = nt * 16 + l15;
      int o2 = (jr << 8) + (ka << 1); o2 ^= (jr & 7) << 4;
      bf16x8 bfr = *(const bf16x8*)(kbuf + o2);
      sacc[nt] = __builtin_amdgcn_mfma_f32_16x16x32_bf16(afr, bfr, sacc[nt], 0, 0, 0);
    }
  }
  __syncthreads();   // all Q reads done before P overwrites qpb

  // softmax, P -> qpb (8KB region)
  #pragma unroll
  for (int rg = 0; rg < 4; ++rg) {
    float mx = -3.0e38f;
    #pragma unroll
    for (int nt = 0; nt < 4; ++nt) mx = fmaxf(mx, sacc[nt][rg]);
    #pragma unroll
    for (int dd = 1; dd < 16; dd <<= 1) mx = fmaxf(mx, __shfl_xor(mx, dd, 64));
    float s = 0.f, e[4];
    #pragma unroll
    for (int nt = 0; nt < 4; ++nt) { e[nt] = __expf((sacc[nt][rg] - mx) * SCALE); s += e[nt]; }
    #pragma unroll
    for (int dd = 1; dd < 16; dd <<= 1) s += __shfl_xor(s, dd, 64);
    float inv = 1.f / s;
    int row = wvid * 16 + rbase + rg;
    #pragma unroll
    for (int nt = 0; nt < 4; ++nt) {
      int col = nt * 16 + l15;
      int off = (row << 7) + (col << 1); off ^= (row & 7) << 4;
      *(unsigned short*)(qpb + off) = f2b(e[nt] * inv);
    }
  }
  __syncthreads();

  // PV
  f32x4 pacc[4][2];
  #pragma unroll
  for (int mt = 0; mt < 4; ++mt)
    #pragma unroll
    for (int nt = 0; nt < 2; ++nt) pacc[mt][nt] = (f32x4){0.f, 0.f, 0.f, 0.f};
  #pragma unroll
  for (int kk = 0; kk < 64; kk += 32) {
    int ka = kk + kl;
    bf16x8 afr[4];
    #pragma unroll
    for (int mt = 0; mt < 4; ++mt) {
      int row = mt * 16 + l15;
      int off = (row << 7) + (ka << 1); off ^= (row & 7) << 4;
      afr[mt] = *(const bf16x8*)(qpb + off);
    }
    bf16x8 bfr[2];
    #pragma unroll
    for (int nt = 0; nt < 2; ++nt) {
      int d = wvid * 32 + nt * 16 + l15;
      int off = (d << 7) + (ka << 1); off ^= (d & 7) << 4;
      bfr[nt] = *(const bf16x8*)(vtb + off);
    }
    #pragma unroll
    for (int mt = 0; mt < 4; ++mt)
      #pragma unroll
      for (int nt = 0; nt < 2; ++nt)
        pacc[mt][nt] = __builtin_amdgcn_mfma_f32_16x16x32_bf16(afr[mt], bfr[nt], pacc[mt][nt], 0, 0, 0);
  }
  // write attn over Q component (valid tokens only; disjoint (tok, head))
  #pragma unroll
  for (int mt = 0; mt < 4; ++mt)
    #pragma unroll
    for (int rg = 0; rg < 4; ++rg) {
      int r = mt * 16 + rbase + rg;
      bool val; int tok = rowtok(r, val);
      if (val) {
        unsigned short* po = qkvs + (size_t)tok * 1536 + h * 128;
        #pragma unroll
        for (int nt = 0; nt < 2; ++nt)
          po[wvid * 32 + nt * 16 + l15] = f2b(pacc[mt][nt][rg]);
      }
    }
}

// ===== K3: m97-style output proj: [103680x512(Q cols)] @ Wo^T + bo ==========
extern "C" __global__ __launch_bounds__(256, 4)
void proj_m97(const unsigned short* __restrict__ qkvs,   // attn in Q cols, stride 1536
              const unsigned short* __restrict__ wo,     // [512][512] bf16
              const float* __restrict__ bo,
              float* __restrict__ out)
{
  __shared__ char As[16384];
  __shared__ char Bs[16384];

  const int tid   = threadIdx.x;
  const int wvid  = tid >> 6;
  const int lane  = tid & 63;
  const int l15   = lane & 15;
  const int rbase = (lane >> 4) << 2;

  // 3240 = 8 * 405; tile-major within XCD chunk (4 col-blocks share A tile)
  const int i    = blockIdx.x;
  const int work = (i & 7) * 405 + (i >> 3);
  const int t0   = (work >> 2) * 128;
  const int j0   = (work & 3) * 128;

  const int lr = lane >> 3;
  const int lc = (lane & 7) ^ lr;
  const unsigned short* gA = qkvs + (size_t)(t0 + wvid * 32 + lr) * 1536 + lc * 8;
  const unsigned short* gB = wo + (size_t)(j0 + wvid * 32 + lr) * 512 + lc * 8;
  char* lA = As + wvid * 4096;
  char* lB = Bs + wvid * 4096;

  f32x4 acc[4][4];
  #pragma unroll
  for (int mt = 0; mt < 4; ++mt)
    #pragma unroll
    for (int nt = 0; nt < 4; ++nt) acc[mt][nt] = (f32x4){0.f, 0.f, 0.f, 0.f};

  const int wr = (wvid >> 1) * 64, wc = (wvid & 1) * 64;

  for (int kk = 0; kk < 512; kk += 64) {
    #pragma unroll
    for (int ii = 0; ii < 4; ++ii) {
      g2lds16(gA + (size_t)ii * 8 * 1536 + kk, lA + ii * 1024);
      g2lds16(gB + (size_t)ii * 8 * 512 + kk, lB + ii * 1024);
    }
    __syncthreads();
    #pragma unroll
    for (int ks = 0; ks < 2; ++ks) {
      const int lchunk = ks * 4 + (lane >> 4);
      bf16x8 afr[4], bfr[4];
      #pragma unroll
      for (int mt = 0; mt < 4; ++mt) {
        int row = wr + mt * 16 + l15;
        afr[mt] = *(const bf16x8*)(As + row * 128 + ((lchunk ^ (row & 7)) << 4));
      }
      #pragma unroll
      for (int nt = 0; nt < 4; ++nt) {
        int col = wc + nt * 16 + l15;
        bfr[nt] = *(const bf16x8*)(Bs + col * 128 + ((lchunk ^ (col & 7)) << 4));
      }
      #pragma unroll
      for (int mt = 0; mt < 4; ++mt)
        #pragma unroll
        for (int nt = 0; nt < 4; ++nt)
          acc[mt][nt] = __builtin_amdgcn_mfma_f32_16x16x32_bf16(afr[mt], bfr[nt], acc[mt][nt], 0, 0, 0);
    }
    __syncthreads();
  }

  #pragma unroll
  for (int nt = 0; nt < 4; ++nt) {
    int col = j0 + wc + nt * 16 + l15;
    float bi = bo[col];
    #pragma unroll
    for (int mt = 0; mt < 4; ++mt)
      #pragma unroll
      for (int rg = 0; rg < 4; ++rg) {
        int row = t0 + wr + mt * 16 + rbase + rg;
        out[(size_t)row * 512 + col] = acc[mt][nt][rg] + bi;
      }
  }
}

// ===== TIER 2 fallback: round-7 fused kernel + window-order proj ============
extern "C" __global__ __launch_bounds__(256, 1)
void qkv_attn(const float* __restrict__ x,
              const unsigned short* __restrict__ wbf,
              const float* __restrict__ bq, const float* __restrict__ bk,
              const float* __restrict__ bv,
              unsigned short* __restrict__ slab)
{
  __shared__ char smem[73728];
  char* qb = smem + 32768;
  char* kb = smem + 49152;
  char* pb = smem + 65536;

  const int tid   = threadIdx.x;
  const int wvid  = tid >> 6;
  const int lane  = tid & 63;
  const int l15   = lane & 15;
  const int kl    = (lane >> 4) << 3;
  const int rbase = (lane >> 4) << 2;

  const int blk = blockIdx.x;
  const int b   = blk / NWIN;
  const int w   = blk - b * NWIN;
  const int wy  = w / GWt, wx = w - wy * GWt;

  for (int it = 0; it < 32; ++it) {
    int f  = it * 256 + tid;
    int r  = f >> 7;
    int c4 = f & 127;
    int gy = wy * 8 + (r >> 3), gx = wx * 8 + (r & 7);
    float4 v = make_float4(0.f, 0.f, 0.f, 0.f);
    if (gy < Ht && gx < Wt)
      v = *(const float4*)(x + ((size_t)b * NTOK + gy * Wt + gx) * C + c4 * 4);
    u16x4 o;
    o[0] = f2b(v.x); o[1] = f2b(v.y); o[2] = f2b(v.z); o[3] = f2b(v.w);
    int lc  = c4 & 63;
    int off = (r << 9) + (lc << 3);
    off ^= (r & 7) << 4;
    off += (c4 >> 6) * 32768;
    *(u16x4*)(smem + off) = o;
  }
  __syncthreads();

  bf16x8 xr[4][8];
  #pragma unroll
  for (int mt = 0; mt < 4; ++mt) {
    int row = mt * 16 + l15;
    #pragma unroll
    for (int s = 0; s < 8; ++s) {
      int off = (row << 9) + ((s * 32 + kl) << 1);
      off ^= (row & 7) << 4;
      xr[mt][s] = *(const bf16x8*)(smem + 32768 + off);
    }
  }
  __syncthreads();

  auto gemm_r = [&](const unsigned short* wm, int h, f32x4 (&acc)[4][2]) {
    #pragma unroll
    for (int mt = 0; mt < 4; ++mt)
      #pragma unroll
      for (int nt = 0; nt < 2; ++nt) acc[mt][nt] = (f32x4){0.f, 0.f, 0.f, 0.f};
    #pragma unroll
    for (int s = 0; s < 16; ++s) {
      int ka = s * 32 + kl;
      bf16x8 afr[4];
      if (s < 8) {
        #pragma unroll
        for (int mt = 0; mt < 4; ++mt) {
          int row = mt * 16 + l15;
          int off = (row << 9) + (ka << 1);
          off ^= (row & 7) << 4;
          afr[mt] = *(const bf16x8*)(smem + off);
        }
      } else {
        #pragma unroll
        for (int mt = 0; mt < 4; ++mt) afr[mt] = xr[mt][s - 8];
      }
      bf16x8 bfr[2];
      #pragma unroll
      for (int nt = 0; nt < 2; ++nt) {
        int jg = h * 128 + wvid * 32 + nt * 16 + l15;
        bfr[nt] = *(const bf16x8*)(wm + (size_t)jg * 512 + ka);
      }
      #pragma unroll
      for (int mt = 0; mt < 4; ++mt)
        #pragma unroll
        for (int nt = 0; nt < 2; ++nt)
          acc[mt][nt] = __builtin_amdgcn_mfma_f32_16x16x32_bf16(afr[mt], bfr[nt], acc[mt][nt], 0, 0, 0);
    }
  };

  auto store_rm = [&](f32x4 (&acc)[4][2], char* base, const float* bias, int h) {
    #pragma unroll
    for (int nt = 0; nt < 2; ++nt) {
      int col = wvid * 32 + nt * 16 + l15;
      float bi = bias[h * 128 + col];
      #pragma unroll
      for (int mt = 0; mt < 4; ++mt)
        #pragma unroll
        for (int rg = 0; rg < 4; ++rg) {
          int row = mt * 16 + rbase + rg;
          int off = (row << 8) + (col << 1);
          off ^= (row & 7) << 4;
          *(unsigned short*)(base + off) = f2b(acc[mt][nt][rg] + bi);
        }
    }
  };

  unsigned short* sl = slab + (size_t)blk * 32768;

  for (int h = 0; h < 4; ++h) {
    {
      f32x4 acc[4][2];
      gemm_r(wbf + 0 * 262144, h, acc);
      store_rm(acc, qb, bq, h);
      gemm_r(wbf + 1 * 262144, h, acc);
      store_rm(acc, kb, bk, h);
    }
    __syncthreads();
    f32x4 vacc[4][2];
    {
      f32x4 sacc[4];
      #pragma unroll
      for (int nt = 0; nt < 4; ++nt) sacc[nt] = (f32x4){0.f, 0.f, 0.f, 0.f};
      #pragma unroll
      for (int kk = 0; kk < 128; kk += 32) {
        int ka = kk + kl;
        int row = wvid * 16 + l15;
        int off = (row << 8) + (ka << 1); off ^= (row & 7) << 4;
        bf16x8 afr = *(const bf16x8*)(qb + off);
        #pragma unroll
        for (int nt = 0; nt < 4; ++nt) {
          int jr = nt * 16 + l15;
          int o2 = (jr << 8) + (ka << 1); o2 ^= (jr & 7) << 4;
          bf16x8 bfr = *(const bf16x8*)(kb + o2);
          sacc[nt] = __builtin_amdgcn_mfma_f32_16x16x32_bf16(afr, bfr, sacc[nt], 0, 0, 0);
        }
      }
      #pragma unroll
      for (int rg = 0; rg < 4; ++rg) {
        float mx = -3.0e38f;
        #pragma unroll
        for (int nt = 0; nt < 4; ++nt) mx = fmaxf(mx, sacc[nt][rg]);
        #pragma unroll
        for (int dd = 1; dd < 16; dd <<= 1) mx = fmaxf(mx, __shfl_xor(mx, dd, 64));
        float s = 0.f, e[4];
        #pragma unroll
        for (int nt = 0; nt < 4; ++nt) { e[nt] = __expf((sacc[nt][rg] - mx) * SCALE); s += e[nt]; }
        #pragma unroll
        for (int dd = 1; dd < 16; dd <<= 1) s += __shfl_xor(s, dd, 64);
        float inv = 1.f / s;
        int row = wvid * 16 + rbase + rg;
        #pragma unroll
        for (int nt = 0; nt < 4; ++nt) {
          int col = nt * 16 + l15;
          int off = (row << 7) + (col << 1); off ^= (row & 7) << 4;
          *(unsigned short*)(pb + off) = f2b(e[nt] * inv);
        }
      }
      gemm_r(wbf + 2 * 262144, h, vacc);
    }
    __syncthreads();
    {
      #pragma unroll
      for (int nt = 0; nt < 2; ++nt) {
        int d = wvid * 32 + nt * 16 + l15;
        float bi = bv[h * 128 + d];
        #pragma unroll
        for (int mt = 0; mt < 4; ++mt) {
          int j0 = mt * 16 + rbase;
          u16x4 pk;
          #pragma unroll
          for (int rg = 0; rg < 4; ++rg) pk[rg] = f2b(vacc[mt][nt][rg] + bi);
          int off = (d << 7) + (j0 << 1); off ^= (d & 7) << 4;
          *(u16x4*)(kb + off) = pk;
        }
      }
    }
    __syncthreads();
    {
      f32x4 pacc[4][2];
      #pragma unroll
      for (int mt = 0; mt < 4; ++mt)
        #pragma unroll
        for (int nt = 0; nt < 2; ++nt) pacc[mt][nt] = (f32x4){0.f, 0.f, 0.f, 0.f};
      #pragma unroll
      for (int kk = 0; kk < 64; kk += 32) {
        int ka = kk + kl;
        bf16x8 afr[4];
        #pragma unroll
        for (int mt = 0; mt < 4; ++mt) {
          int row = mt * 16 + l15;
          int off = (row << 7) + (ka << 1); off ^= (row & 7) << 4;
          afr[mt] = *(const bf16x8*)(pb + off);
        }
        bf16x8 bfr[2];
        #pragma unroll
        for (int nt = 0; nt < 2; ++nt) {
          int d = wvid * 32 + nt * 16 + l15;
          int off = (d << 7) + (ka << 1); off ^= (d & 7) << 4;
          bfr[nt] = *(const bf16x8*)(kb + off);
        }
        #pragma unroll
        for (int mt = 0; mt < 4; ++mt)
          #pragma unroll
          for (int nt = 0; nt < 2; ++nt)
            pacc[mt][nt] = __builtin_amdgcn_mfma_f32_16x16x32_bf16(afr[mt], bfr[nt], pacc[mt][nt], 0, 0, 0);
      }
      #pragma unroll
      for (int nt = 0; nt < 2; ++nt) {
        int d = wvid * 32 + nt * 16 + l15;
        #pragma unroll
        for (int mt = 0; mt < 4; ++mt)
          #pragma unroll
          for (int rg = 0; rg < 4; ++rg) {
            int row = mt * 16 + rbase + rg;
            sl[row * 512 + h * 128 + d] = f2b(pacc[mt][nt][rg]);
          }
      }
    }
    __syncthreads();
  }
}

extern "C" __global__ __launch_bounds__(256, 2)
void proj_win(const unsigned short* __restrict__ slab,
              const unsigned short* __restrict__ wo,
              const float* __restrict__ bo,
              float* __restrict__ out)
{
  __shared__ char smem[65536];
  const int tid   = threadIdx.x;
  const int wvid  = tid >> 6;
  const int lane  = tid & 63;
  const int l15   = lane & 15;
  const int kl    = (lane >> 4) << 3;
  const int rbase = (lane >> 4) << 2;

  const int blk = blockIdx.x;
  const int b   = blk / NWIN;
  const int w   = blk - b * NWIN;
  const int wy  = w / GWt, wx = w - wy * GWt;

  const unsigned short* src = slab + (size_t)blk * 32768;
  for (int it = 0; it < 16; ++it) {
    int f  = it * 256 + tid;
    int r  = f >> 6;
    int c8 = f & 63;
    bf16x8 v = *(const bf16x8*)(src + r * 512 + c8 * 8);
    int off = (r << 10) + (c8 << 4);
    off ^= (r & 7) << 4;
    *(bf16x8*)(smem + off) = v;
  }
  __syncthreads();

  for (int half = 0; half < 2; ++half) {
    f32x4 acc[4][4];
    #pragma unroll
    for (int mt = 0; mt < 4; ++mt)
      #pragma unroll
      for (int nt = 0; nt < 4; ++nt) acc[mt][nt] = (f32x4){0.f, 0.f, 0.f, 0.f};
    #pragma unroll 2
    for (int kk = 0; kk < 512; kk += 32) {
      int ka = kk + kl;
      bf16x8 afr[4];
      #pragma unroll
      for (int mt = 0; mt < 4; ++mt) {
        int row = mt * 16 + l15;
        int off = (row << 10) + (ka << 1); off ^= (row & 7) << 4;
        afr[mt] = *(const bf16x8*)(smem + off);
      }
      bf16x8 bfr[4];
      #pragma unroll
      for (int nt = 0; nt < 4; ++nt) {
        int j = wvid * 128 + half * 64 + nt * 16 + l15;
        bfr[nt] = *(const bf16x8*)(wo + (size_t)j * 512 + ka);
      }
      #pragma unroll
      for (int mt = 0; mt < 4; ++mt)
        #pragma unroll
        for (int nt = 0; nt < 4; ++nt)
          acc[mt][nt] = __builtin_amdgcn_mfma_f32_16x16x32_bf16(afr[mt], bfr[nt], acc[mt][nt], 0, 0, 0);
    }
    #pragma unroll
    for (int mt = 0; mt < 4; ++mt)
      #pragma unroll
      for (int rg = 0; rg < 4; ++rg) {
        int r = mt * 16 + rbase + rg;
        int gy = wy * 8 + (r >> 3), gx = wx * 8 + (r & 7);
        if (gy < Ht && gx < Wt) {
          float* po = out + ((size_t)b * NTOK + gy * Wt + gx) * C;
          #pragma unroll
          for (int nt = 0; nt < 4; ++nt) {
            int j = wvid * 128 + half * 64 + nt * 16 + l15;
            po[j] = acc[mt][nt][rg] + bo[j];
          }
        }
      }
  }
}

extern "C" void kernel_launch(void* const* d_in, const int* in_sizes, int n_in,
                              void* d_out, int out_size, void* d_ws, size_t ws_size,
                              hipStream_t stream) {
  const float* x  = (const float*)d_in[0];
  const float* Wq = (const float*)d_in[2];
  const float* bq = (const float*)d_in[3];
  const float* Wk = (const float*)d_in[4];
  const float* bk = (const float*)d_in[5];
  const float* Wv = (const float*)d_in[6];
  const float* bv = (const float*)d_in[7];
  const float* Wo = (const float*)d_in[8];
  const float* bo = (const float*)d_in[9];
  unsigned short* wbf = (unsigned short*)d_ws;

  cvt_weights<<<1024, 256, 0, stream>>>(Wq, Wk, Wv, Wo, wbf);

  const size_t need_full = (WOFF + QKVE) * 2;     // ~321 MB
  const size_t need_r7   = (WOFF + SLABE) * 2;    // ~119 MB

  if (ws_size >= need_full) {
    unsigned short* qkvs = wbf + WOFF;
    unsigned short* xb   = (unsigned short*)d_out;   // d_out as bf16-x scratch
    xcvt_tok<<<MROWS * 512 / 2048, 256, 0, stream>>>(x, xb);
    qkv_m97<<<9720, 256, 0, stream>>>(xb, wbf, bq, bk, bv, qkvs);
    attn_tok<<<dim3(NBLK, 4), 256, 0, stream>>>(qkvs, bk, bv);
    proj_m97<<<3240, 256, 0, stream>>>(qkvs, wbf + 3 * 262144, bo, (float*)d_out);
  } else if (ws_size >= need_r7) {
    unsigned short* slab = wbf + WOFF;
    qkv_attn<<<NBLK, 256, 0, stream>>>(x, wbf, bq, bk, bv, slab);
    proj_win<<<NBLK, 256, 0, stream>>>(slab, wbf + 3 * 262144, bo, (float*)d_out);
  }
}